// Round 1
// baseline (984.967 us; speedup 1.0000x reference)
//
#include <hip/hip_runtime.h>
#include <hip/hip_bf16.h>

typedef __hip_bfloat16 bf16;

typedef __attribute__((ext_vector_type(8))) short frag8;
typedef __attribute__((ext_vector_type(4))) float f32x4;

__device__ __forceinline__ bf16 f2bf(float f) { return __float2bfloat16(f); }

__device__ __forceinline__ float u16f(unsigned short u) {
  union { unsigned int i; float f; } c; c.i = ((unsigned int)u) << 16; return c.f;
}
__device__ __forceinline__ unsigned short bfbits(float f) {
  union { bf16 b; unsigned short u; } c; c.b = __float2bfloat16(f); return c.u;
}
__device__ __forceinline__ float tof(float x) { return x; }
__device__ __forceinline__ float tof(bf16 x)  { return __bfloat162float(x); }

// async 16B global->LDS copy (m97 pattern)
__device__ __forceinline__ void gload_lds16(const bf16* g, short* l) {
  __builtin_amdgcn_global_load_lds(
      (const __attribute__((address_space(1))) void*)g,
      (__attribute__((address_space(3))) void*)l, 16, 0, 0);
}

#define EP_PLAIN 0
#define EP_QKV   1
#define EP_RK    2

// batched fp32 -> bf16 convert: 8 segments in one launch
struct CvtArgs {
  const float* src[8];
  bf16* dst[8];
  int cum[9];          // cumulative n4 boundaries
};
__global__ __launch_bounds__(256)
void cvt8(CvtArgs a)
{
  const int i = blockIdx.x * 256 + threadIdx.x;
  if (i >= a.cum[8]) return;
  int seg = 7;
  #pragma unroll
  for (int s2 = 6; s2 >= 0; --s2) if (i < a.cum[s2 + 1]) seg = s2;
  const int o = i - a.cum[seg];
  float4 v = ((const float4*)a.src[seg])[o];
  ushort4 u;
  u.x = bfbits(v.x); u.y = bfbits(v.y); u.z = bfbits(v.z); u.w = bfbits(v.w);
  ((ushort4*)a.dst[seg])[o] = u;
}

// MFMA GEMM: C[M,N] = A[M,K] @ W[N,K]^T, bf16 in, fp32 accum.
// 128x128 tile, BK=32, 4 waves (2x2), global_load_lds staging (R6).
template<typename TRES>
__global__ __launch_bounds__(256)
void mgemm(const bf16* __restrict__ A, const bf16* __restrict__ W,
           const float* __restrict__ bias, const TRES* __restrict__ res,
           bf16* __restrict__ out,
           bf16* __restrict__ qwb, bf16* __restrict__ qrb,
           bf16* __restrict__ kbo, bf16* __restrict__ vto,
           const float* __restrict__ rwbias, const float* __restrict__ rrbias,
           int M, int N, int K, int mode, int relu)
{
  __shared__ __align__(16) short sA[128 * 32];
  __shared__ __align__(16) short sB[128 * 32];
  const int tid  = threadIdx.x;
  const int lane = tid & 63;
  const int wave = tid >> 6;
  const int quad = lane >> 4;
  const int l15  = lane & 15;
  const int m0 = blockIdx.y * 128;
  const int n0 = blockIdx.x * 128;
  const int wm = (wave >> 1) * 64;
  const int wn = (wave & 1) * 64;

  const int lr = tid >> 2;
  const int lc = (tid & 3) << 3;

  const bf16* aptr0 = A + (size_t)(m0 + lr) * K + lc;
  const bf16* aptr1 = aptr0 + (size_t)64 * K;
  const bf16* wptr0 = W + (size_t)(n0 + lr) * K + lc;
  const bf16* wptr1 = wptr0 + (size_t)64 * K;

  short* ldsA0 = &sA[wave * 512];
  short* ldsA1 = &sA[2048 + wave * 512];
  short* ldsB0 = &sB[wave * 512];
  short* ldsB1 = &sB[2048 + wave * 512];

  f32x4 acc[4][4] = {};

  for (int kk = 0; kk < K; kk += 32) {
    __syncthreads();
    gload_lds16(aptr0 + kk, ldsA0);
    gload_lds16(aptr1 + kk, ldsA1);
    gload_lds16(wptr0 + kk, ldsB0);
    gload_lds16(wptr1 + kk, ldsB1);
    __syncthreads();
    frag8 af[4], bfr[4];
    #pragma unroll
    for (int t = 0; t < 4; ++t) {
      af[t]  = *(const frag8*)&sA[(wm + t * 16 + l15) * 32 + quad * 8];
      bfr[t] = *(const frag8*)&sB[(wn + t * 16 + l15) * 32 + quad * 8];
    }
    #pragma unroll
    for (int mi = 0; mi < 4; ++mi)
      #pragma unroll
      for (int ni = 0; ni < 4; ++ni)
        acc[mi][ni] = __builtin_amdgcn_mfma_f32_16x16x32_bf16(
            af[mi], bfr[ni], acc[mi][ni], 0, 0, 0);
  }

  #pragma unroll
  for (int mi = 0; mi < 4; ++mi) {
    #pragma unroll
    for (int reg = 0; reg < 4; ++reg) {
      const int row = m0 + wm + mi * 16 + quad * 4 + reg;
      if (mode == EP_PLAIN) {
        bf16* orow = out + (size_t)row * N;
        const TRES* rrow = res ? res + (size_t)row * N : nullptr;
        #pragma unroll
        for (int ni = 0; ni < 4; ++ni) {
          const int col = n0 + wn + ni * 16 + l15;
          float v = acc[mi][ni][reg];
          if (bias) v += bias[col];
          if (relu) v = fmaxf(v, 0.f);
          if (rrow) v += tof(rrow[col]);
          orow[col] = f2bf(v);
        }
      } else if (mode == EP_QKV) {
        const int t = row >> 3, bb = row & 7;
        #pragma unroll
        for (int ni = 0; ni < 4; ++ni) {
          const int col = n0 + wn + ni * 16 + l15;
          const float v = acc[mi][ni][reg];
          const int seg = col >> 10;
          const int cl  = col & 1023;
          const int hn  = cl >> 6, d = cl & 63;
          if (seg == 0) {
            if (t >= 512) {
              const size_t idx = (((size_t)bb * 16 + hn) * 512 + (t - 512)) * 64 + d;
              qwb[idx] = f2bf(v + rwbias[cl]);
              qrb[idx] = f2bf(v + rrbias[cl]);
            }
          } else if (seg == 1) {
            kbo[(((size_t)bb * 16 + hn) * 1024 + t) * 64 + d] = f2bf(v);
          } else {
            vto[(((size_t)bb * 16 + hn) * 64 + d) * 1024 + t] = f2bf(v);
          }
        }
      } else { // EP_RK
        #pragma unroll
        for (int ni = 0; ni < 4; ++ni) {
          const int col = n0 + wn + ni * 16 + l15;
          const int hn = col >> 6, d = col & 63;
          qwb[((size_t)hn * 1024 + row) * 64 + d] = f2bf(acc[mi][ni][reg]);
        }
      }
    }
  }
}

// Fused MFMA attention v4: split-KV inside the block.
// R6 analysis: fattn was latency-bound (MfmaUtil 5%, VALUBusy 14%, HBM 6%,
// occupancy 40% == the grid-limited 4 waves/SIMD cap). v4 halves the rows
// per block (32) and splits the j-range across wave pairs:
//   waves 0,1: j-tiles 0..3  (never masked: j<512 <= i+512 for all i)
//   waves 2,3: j-tiles 4..nsteps-1 (1..4 tiles, masked)
// Partials (m, l, unnormalized O) exchanged through p_lds recast as float
// (1056 floats needed <= 1088 per wave quarter). Grid 2048 blocks -> 8192
// waves -> 8 waves/SIMD. __launch_bounds__(256,8) pins VGPR<=64 (measured
// count was exactly 64) so all 8 blocks/CU fit; LDS 17.4KB*8 = 139KB <= 160KB.
__global__ __launch_bounds__(256, 8)
void fattn(const bf16* __restrict__ qw, const bf16* __restrict__ qr,
           const bf16* __restrict__ kb, const bf16* __restrict__ vT,
           const bf16* __restrict__ rk, bf16* __restrict__ avec)
{
  __shared__ __align__(16) unsigned short p_lds[4][16][136]; // 17408 B
  const int tid  = threadIdx.x;
  const int wave = tid >> 6, lane = tid & 63;
  const int quad = lane >> 4, l15 = lane & 15;
  // XCD-locality decode: bid = r + 8*(phi + 16*ib), pair = r + 8*phi
  const int bid = blockIdx.x;
  const int r_  = bid & 7;
  const int s_  = bid >> 3;
  const int phi = s_ & 15;
  const int ib  = s_ >> 4;            // i-block 0..15 (32 rows each)
  const int pr  = r_ + 8 * phi;       // (h,b) pair 0..127
  const int h   = pr & 15;
  const int b   = pr >> 4;
  const int i0  = ib * 32;
  const int w01   = wave & 1;         // which 16-row half of the i-block
  const int jhalf = wave >> 1;        // 0: j-tiles 0-3, 1: j-tiles 4..
  const int iw  = i0 + w01 * 16;
  const size_t bh = (size_t)b * 16 + h;
  const bf16* kp = kb + bh * 1024 * 64;
  const bf16* vp = vT + bh * 64 * 1024;
  const bf16* rp = rk + (size_t)h * 1024 * 64;

  frag8 aqw[2], aqr[2];
  {
    const bf16* r0 = qw + (bh * 512 + iw + l15) * 64 + quad * 8;
    aqw[0] = *(const frag8*)r0;
    aqw[1] = *(const frag8*)(r0 + 32);
    const bf16* r1 = qr + (bh * 512 + iw + l15) * 64 + quad * 8;
    aqr[0] = *(const frag8*)r1;
    aqr[1] = *(const frag8*)(r1 + 32);
  }

  f32x4 accO[4] = {};
  float m_run[4], l_run[4];
  #pragma unroll
  for (int rg = 0; rg < 4; ++rg) { m_run[rg] = -INFINITY; l_run[rg] = 0.f; }

  // per-wave j-tile range
  const int jt_beg = jhalf ? 4 : 0;
  const int jt_end = jhalf ? (((iw + 15 + 512) >> 7) + 1) : 4;
  const int offb   = 15 + l15 - quad * 4;

  for (int jt = jt_beg; jt < jt_end; ++jt) {
    const int j0 = jt << 7;
    // ---- AC scores (16 independent K loads + MFMAs) ----
    f32x4 accS[8] = {};
    #pragma unroll
    for (int ns = 0; ns < 8; ++ns) {
      const bf16* krow = kp + (size_t)(j0 + ns * 16 + l15) * 64 + quad * 8;
      frag8 bk0 = *(const frag8*)krow;
      frag8 bk1 = *(const frag8*)(krow + 32);
      accS[ns] = __builtin_amdgcn_mfma_f32_16x16x32_bf16(aqw[0], bk0, accS[ns], 0,0,0);
      accS[ns] = __builtin_amdgcn_mfma_f32_16x16x32_bf16(aqw[1], bk1, accS[ns], 0,0,0);
    }
    // ---- BD: all 9 p-subtiles materialized (independent loads + MFMAs) ----
    const int pbase = 496 + j0 - iw;
    f32x4 bsub[9];
    #pragma unroll
    for (int ns = 0; ns < 9; ++ns) {
      const int prow = min(pbase + ns * 16 + l15, 1023);
      const bf16* rrow = rp + (size_t)prow * 64 + quad * 8;
      frag8 br0 = *(const frag8*)rrow;
      frag8 br1 = *(const frag8*)(rrow + 32);
      f32x4 z = {};
      z = __builtin_amdgcn_mfma_f32_16x16x32_bf16(aqr[0], br0, z, 0,0,0);
      bsub[ns] = __builtin_amdgcn_mfma_f32_16x16x32_bf16(aqr[1], br1, z, 0,0,0);
    }
    // ---- in-register shift + combine + mask + tile max ----
    float tmax[4] = {-INFINITY, -INFINITY, -INFINITY, -INFINITY};
    #pragma unroll
    for (int ns = 0; ns < 8; ++ns) {
      #pragma unroll
      for (int rg = 0; rg < 4; ++rg) {
        const int o    = offb - rg;                 // [0,30]
        const int srcl = (quad << 4) | (o & 15);
        const float lo = __shfl(bsub[ns][rg],     srcl, 64);
        const float hi = __shfl(bsub[ns + 1][rg], srcl, 64);
        const float bd = (o & 16) ? hi : lo;
        float s = (accS[ns][rg] + bd) * 0.125f;
        if (jhalf) {  // low half (j<512) is never masked: j <= 511 < i+512
          const int j = j0 + ns * 16 + l15;
          s = (j > iw + quad * 4 + rg + 512) ? -INFINITY : s;
        }
        accS[ns][rg] = s;
        tmax[rg] = fmaxf(tmax[rg], s);
      }
    }
    #pragma unroll
    for (int off = 1; off < 16; off <<= 1)
      #pragma unroll
      for (int rg = 0; rg < 4; ++rg)
        tmax[rg] = fmaxf(tmax[rg], __shfl_xor(tmax[rg], off, 64));
    // ---- online softmax update ----
    float alpha[4], tsum[4] = {0.f, 0.f, 0.f, 0.f};
    #pragma unroll
    for (int rg = 0; rg < 4; ++rg) {
      const float nm = fmaxf(m_run[rg], tmax[rg]);
      alpha[rg] = __expf(m_run[rg] - nm);
      m_run[rg] = nm;
    }
    #pragma unroll
    for (int ns = 0; ns < 8; ++ns)
      #pragma unroll
      for (int rg = 0; rg < 4; ++rg) {
        const int rl = quad * 4 + rg;
        const float pv = __expf(accS[ns][rg] - m_run[rg]);
        tsum[rg] += pv;
        p_lds[wave][rl][ns * 16 + l15] = bfbits(pv);
      }
    #pragma unroll
    for (int off = 1; off < 16; off <<= 1)
      #pragma unroll
      for (int rg = 0; rg < 4; ++rg)
        tsum[rg] += __shfl_xor(tsum[rg], off, 64);
    #pragma unroll
    for (int rg = 0; rg < 4; ++rg)
      l_run[rg] = l_run[rg] * alpha[rg] + tsum[rg];
    #pragma unroll
    for (int nd = 0; nd < 4; ++nd)
      #pragma unroll
      for (int rg = 0; rg < 4; ++rg)
        accO[nd][rg] *= alpha[rg];
    __builtin_amdgcn_wave_barrier();
    // ---- PV ----
    #pragma unroll
    for (int ks = 0; ks < 4; ++ks) {
      frag8 ap = *(const frag8*)&p_lds[wave][l15][ks * 32 + quad * 8];
      #pragma unroll
      for (int nd = 0; nd < 4; ++nd) {
        const bf16* vrow = vp + (size_t)(nd * 16 + l15) * 1024 + j0 + ks * 32 + quad * 8;
        frag8 bv = *(const frag8*)vrow;
        accO[nd] = __builtin_amdgcn_mfma_f32_16x16x32_bf16(ap, bv, accO[nd], 0,0,0);
      }
    }
    __builtin_amdgcn_wave_barrier();
  }

  // ---- cross-wave combine: wave w (j-tiles 0-3) + wave w+2 (j-tiles 4+) ----
  // Exchange through p_lds recast as float: 4352 floats total, 1088 per wave
  // region; each upper wave needs 1024 (O) + 32 (m,l) = 1056 floats.
  float* xch = (float*)&p_lds[0][0][0];
  if (jhalf) {
    float* mybase = xch + wave * 1088;
    #pragma unroll
    for (int rg = 0; rg < 4; ++rg) {
      const int row = quad * 4 + rg;
      #pragma unroll
      for (int nd = 0; nd < 4; ++nd)
        mybase[row * 64 + nd * 16 + l15] = accO[nd][rg];
      if (l15 == 0) {
        mybase[1024 + row * 2]     = m_run[rg];
        mybase[1024 + row * 2 + 1] = l_run[rg];
      }
    }
  }
  __syncthreads();
  if (!jhalf) {
    const float* pb = xch + (wave + 2) * 1088;
    #pragma unroll
    for (int rg = 0; rg < 4; ++rg) {
      const int row = quad * 4 + rg;
      const float mB = pb[1024 + row * 2];
      const float lB = pb[1024 + row * 2 + 1];
      const float m  = fmaxf(m_run[rg], mB);
      const float aA = __expf(m_run[rg] - m);
      const float aB = __expf(mB - m);
      const float inv = 1.f / (l_run[rg] * aA + lB * aB);
      const int i = iw + row;
      #pragma unroll
      for (int nd = 0; nd < 4; ++nd) {
        const int d = nd * 16 + l15;
        const float oB = pb[row * 64 + d];
        avec[((size_t)i * 8 + b) * 1024 + h * 64 + d] =
            f2bf((accO[nd][rg] * aA + oB * aB) * inv);
      }
    }
  }
}

// row LayerNorm over 1024 cols; one block per row.
template<typename TOUT>
__global__ __launch_bounds__(256)
void ln_kernel(const bf16* __restrict__ x, const float* __restrict__ g,
               const float* __restrict__ be, TOUT* __restrict__ out)
{
  __shared__ float red0[4];
  __shared__ float red1[4];
  const int row = blockIdx.x;
  const int tid = threadIdx.x;
  const bf16* xr = x + (size_t)row * 1024;
  ushort4 u = *(const ushort4*)(xr + (tid << 2));
  const float v0 = u16f(u.x), v1 = u16f(u.y), v2 = u16f(u.z), v3 = u16f(u.w);
  float sum = v0 + v1 + v2 + v3;
  #pragma unroll
  for (int off = 1; off < 64; off <<= 1) sum += __shfl_xor(sum, off, 64);
  if ((tid & 63) == 0) red0[tid >> 6] = sum;
  __syncthreads();
  const float mu = (red0[0] + red0[1] + red0[2] + red0[3]) * (1.f / 1024.f);
  const float d0 = v0 - mu, d1 = v1 - mu, d2 = v2 - mu, d3 = v3 - mu;
  float sq = d0*d0 + d1*d1 + d2*d2 + d3*d3;
  #pragma unroll
  for (int off = 1; off < 64; off <<= 1) sq += __shfl_xor(sq, off, 64);
  if ((tid & 63) == 0) red1[tid >> 6] = sq;
  __syncthreads();
  const float var = (red1[0] + red1[1] + red1[2] + red1[3]) * (1.f / 1024.f);
  const float inv = 1.f / sqrtf(var + 1e-5f);
  const int c = tid << 2;
  float4 ug = *(const float4*)(g + c);
  float4 ub = *(const float4*)(be + c);
  TOUT* orow = out + (size_t)row * 1024;
  orow[c+0] = (TOUT)(d0 * inv * ug.x + ub.x);
  orow[c+1] = (TOUT)(d1 * inv * ug.y + ub.y);
  orow[c+2] = (TOUT)(d2 * inv * ug.z + ub.z);
  orow[c+3] = (TOUT)(d3 * inv * ug.w + ub.w);
}

extern "C" void kernel_launch(void* const* d_in, const int* in_sizes, int n_in,
                              void* d_out, int out_size, void* d_ws, size_t ws_size,
                              hipStream_t stream)
{
  const float* w    = (const float*)d_in[0];
  const float* r    = (const float*)d_in[1];
  const float* rwb  = (const float*)d_in[2];
  const float* rrb  = (const float*)d_in[3];
  const float* mems = (const float*)d_in[4];
  // d_in[5] = attn_mask: deterministic (j > i + 512), computed in-kernel
  const float* Wqkv = (const float*)d_in[6];
  const float* Wr   = (const float*)d_in[7];
  const float* Wo   = (const float*)d_in[8];
  const float* ln1g = (const float*)d_in[9];
  const float* ln1b = (const float*)d_in[10];
  const float* W1   = (const float*)d_in[11];
  const float* b1   = (const float*)d_in[12];
  const float* W2   = (const float*)d_in[13];
  const float* b2   = (const float*)d_in[14];
  const float* ln2g = (const float*)d_in[15];
  const float* ln2b = (const float*)d_in[16];

  // Workspace (bf16), liveness-aliased, peak 94 MiB (layout unchanged from R5)
  const size_t MB = 1u << 20;
  char* p = (char*)d_ws;
  bf16* catb  = (bf16*)(p +  0 * MB);
  bf16* wqkvb = (bf16*)(p + 16 * MB);
  bf16* wrb   = (bf16*)(p + 22 * MB);
  bf16* wob   = (bf16*)(p + 24 * MB);
  bf16* w1b   = (bf16*)(p + 26 * MB);
  bf16* w2b   = (bf16*)(p + 34 * MB);
  bf16* qwbuf = (bf16*)(p + 42 * MB);
  bf16* qrbuf = (bf16*)(p + 50 * MB);
  bf16* kbuf  = (bf16*)(p + 58 * MB);
  bf16* vTbuf = (bf16*)(p + 74 * MB);
  bf16* rkbuf = (bf16*)(p + 90 * MB);
  bf16* rb    = (bf16*)(p + 92 * MB);
  bf16* avec  = (bf16*)(p +  0 * MB);
  bf16* x1    = (bf16*)(p +  8 * MB);
  bf16* o1    = (bf16*)(p + 42 * MB);
  bf16* x2    = (bf16*)(p + 50 * MB);
  bf16* h     = (bf16*)(p + 58 * MB);

  dim3 blk(256);
  // 0. fp32 -> bf16 converts (one batched launch)
  {
    CvtArgs a;
    const int n4w = (4096 * 1024) / 4, n4r = (1024 * 1024) / 4,
              n4qkv = (3072 * 1024) / 4;
    a.src[0] = mems; a.dst[0] = catb;                        int n0_ = n4w;
    a.src[1] = w;    a.dst[1] = catb + (size_t)4096 * 1024;  int n1_ = n4w;
    a.src[2] = r;    a.dst[2] = rb;                          int n2_ = n4r;
    a.src[3] = Wqkv; a.dst[3] = wqkvb;                       int n3_ = n4qkv;
    a.src[4] = Wr;   a.dst[4] = wrb;                         int n4_ = n4r;
    a.src[5] = Wo;   a.dst[5] = wob;                         int n5_ = n4r;
    a.src[6] = W1;   a.dst[6] = w1b;                         int n6_ = n4w;
    a.src[7] = W2;   a.dst[7] = w2b;                         int n7_ = n4w;
    const int ns_[8] = {n0_, n1_, n2_, n3_, n4_, n5_, n6_, n7_};
    a.cum[0] = 0;
    for (int s2 = 0; s2 < 8; ++s2) a.cum[s2 + 1] = a.cum[s2] + ns_[s2];
    cvt8<<<dim3((a.cum[8] + 255) / 256), blk, 0, stream>>>(a);
  }

  // 1. heads = cat @ Wqkv^T -> scatter qw/qr (biases added), kb, vT
  mgemm<float><<<dim3(24, 64), blk, 0, stream>>>(catb, wqkvb, nullptr, (const float*)nullptr,
        nullptr, qwbuf, qrbuf, kbuf, vTbuf, rwb, rrb, 8192, 3072, 1024, EP_QKV, 0);
  // 2. rk = r @ Wr^T -> (h,p,d)
  mgemm<float><<<dim3(8, 8), blk, 0, stream>>>(rb, wrb, nullptr, (const float*)nullptr,
        nullptr, rkbuf, nullptr, nullptr, nullptr, nullptr, nullptr,
        1024, 1024, 1024, EP_RK, 0);
  // 3. fused MFMA attention -> avec (2048 blocks, split-KV, XCD-swizzled)
  fattn<<<dim3(2048), blk, 0, stream>>>(qwbuf, qrbuf, kbuf, vTbuf, rkbuf, avec);
  // 4. x1 = w + avec @ Wo^T
  mgemm<float><<<dim3(8, 32), blk, 0, stream>>>(avec, wob, nullptr, w,
        x1, nullptr, nullptr, nullptr, nullptr, nullptr, nullptr,
        4096, 1024, 1024, EP_PLAIN, 0);
  // 5. out1 = LN(x1)
  ln_kernel<bf16><<<dim3(4096), blk, 0, stream>>>(x1, ln1g, ln1b, o1);
  // 6. h = relu(out1 @ W1^T + b1)
  mgemm<float><<<dim3(32, 32), blk, 0, stream>>>(o1, w1b, b1, (const float*)nullptr,
        h, nullptr, nullptr, nullptr, nullptr, nullptr, nullptr,
        4096, 4096, 1024, EP_PLAIN, 1);
  // 7. x2 = out1 + h @ W2^T + b2
  mgemm<bf16><<<dim3(8, 32), blk, 0, stream>>>(h, w2b, b2, o1,
        x2, nullptr, nullptr, nullptr, nullptr, nullptr, nullptr,
        4096, 1024, 4096, EP_PLAIN, 0);
  // 8. out = LN(x2) -> fp32
  ln_kernel<float><<<dim3(4096), blk, 0, stream>>>(x2, ln2g, ln2b, (float*)d_out);
}

// Round 2
// 693.950 us; speedup vs baseline: 1.4194x; 1.4194x over previous
//
#include <hip/hip_runtime.h>
#include <hip/hip_bf16.h>

typedef __hip_bfloat16 bf16;

typedef __attribute__((ext_vector_type(8))) short frag8;
typedef __attribute__((ext_vector_type(4))) float f32x4;

__device__ __forceinline__ bf16 f2bf(float f) { return __float2bfloat16(f); }

__device__ __forceinline__ float u16f(unsigned short u) {
  union { unsigned int i; float f; } c; c.i = ((unsigned int)u) << 16; return c.f;
}
__device__ __forceinline__ unsigned short bfbits(float f) {
  union { bf16 b; unsigned short u; } c; c.b = __float2bfloat16(f); return c.u;
}
__device__ __forceinline__ float tof(float x) { return x; }
__device__ __forceinline__ float tof(bf16 x)  { return __bfloat162float(x); }

// async 16B global->LDS copy (m97 pattern)
__device__ __forceinline__ void gload_lds16(const bf16* g, short* l) {
  __builtin_amdgcn_global_load_lds(
      (const __attribute__((address_space(1))) void*)g,
      (__attribute__((address_space(3))) void*)l, 16, 0, 0);
}

#define EP_PLAIN 0
#define EP_QKV   1
#define EP_RK    2

// batched fp32 -> bf16 convert: 8 segments in one launch
struct CvtArgs {
  const float* src[8];
  bf16* dst[8];
  int cum[9];          // cumulative n4 boundaries
};
__global__ __launch_bounds__(256)
void cvt8(CvtArgs a)
{
  const int i = blockIdx.x * 256 + threadIdx.x;
  if (i >= a.cum[8]) return;
  int seg = 7;
  #pragma unroll
  for (int s2 = 6; s2 >= 0; --s2) if (i < a.cum[s2 + 1]) seg = s2;
  const int o = i - a.cum[seg];
  float4 v = ((const float4*)a.src[seg])[o];
  ushort4 u;
  u.x = bfbits(v.x); u.y = bfbits(v.y); u.z = bfbits(v.z); u.w = bfbits(v.w);
  ((ushort4*)a.dst[seg])[o] = u;
}

// MFMA GEMM: C[M,N] = A[M,K] @ W[N,K]^T, bf16 in, fp32 accum.
// 128x128 tile, BK=32, 4 waves (2x2), global_load_lds staging (R6).
template<typename TRES>
__global__ __launch_bounds__(256)
void mgemm(const bf16* __restrict__ A, const bf16* __restrict__ W,
           const float* __restrict__ bias, const TRES* __restrict__ res,
           bf16* __restrict__ out,
           bf16* __restrict__ qwb, bf16* __restrict__ qrb,
           bf16* __restrict__ kbo, bf16* __restrict__ vto,
           const float* __restrict__ rwbias, const float* __restrict__ rrbias,
           int M, int N, int K, int mode, int relu)
{
  __shared__ __align__(16) short sA[128 * 32];
  __shared__ __align__(16) short sB[128 * 32];
  const int tid  = threadIdx.x;
  const int lane = tid & 63;
  const int wave = tid >> 6;
  const int quad = lane >> 4;
  const int l15  = lane & 15;
  const int m0 = blockIdx.y * 128;
  const int n0 = blockIdx.x * 128;
  const int wm = (wave >> 1) * 64;
  const int wn = (wave & 1) * 64;

  const int lr = tid >> 2;
  const int lc = (tid & 3) << 3;

  const bf16* aptr0 = A + (size_t)(m0 + lr) * K + lc;
  const bf16* aptr1 = aptr0 + (size_t)64 * K;
  const bf16* wptr0 = W + (size_t)(n0 + lr) * K + lc;
  const bf16* wptr1 = wptr0 + (size_t)64 * K;

  short* ldsA0 = &sA[wave * 512];
  short* ldsA1 = &sA[2048 + wave * 512];
  short* ldsB0 = &sB[wave * 512];
  short* ldsB1 = &sB[2048 + wave * 512];

  f32x4 acc[4][4] = {};

  for (int kk = 0; kk < K; kk += 32) {
    __syncthreads();
    gload_lds16(aptr0 + kk, ldsA0);
    gload_lds16(aptr1 + kk, ldsA1);
    gload_lds16(wptr0 + kk, ldsB0);
    gload_lds16(wptr1 + kk, ldsB1);
    __syncthreads();
    frag8 af[4], bfr[4];
    #pragma unroll
    for (int t = 0; t < 4; ++t) {
      af[t]  = *(const frag8*)&sA[(wm + t * 16 + l15) * 32 + quad * 8];
      bfr[t] = *(const frag8*)&sB[(wn + t * 16 + l15) * 32 + quad * 8];
    }
    #pragma unroll
    for (int mi = 0; mi < 4; ++mi)
      #pragma unroll
      for (int ni = 0; ni < 4; ++ni)
        acc[mi][ni] = __builtin_amdgcn_mfma_f32_16x16x32_bf16(
            af[mi], bfr[ni], acc[mi][ni], 0, 0, 0);
  }

  #pragma unroll
  for (int mi = 0; mi < 4; ++mi) {
    #pragma unroll
    for (int reg = 0; reg < 4; ++reg) {
      const int row = m0 + wm + mi * 16 + quad * 4 + reg;
      if (mode == EP_PLAIN) {
        bf16* orow = out + (size_t)row * N;
        const TRES* rrow = res ? res + (size_t)row * N : nullptr;
        #pragma unroll
        for (int ni = 0; ni < 4; ++ni) {
          const int col = n0 + wn + ni * 16 + l15;
          float v = acc[mi][ni][reg];
          if (bias) v += bias[col];
          if (relu) v = fmaxf(v, 0.f);
          if (rrow) v += tof(rrow[col]);
          orow[col] = f2bf(v);
        }
      } else if (mode == EP_QKV) {
        const int t = row >> 3, bb = row & 7;
        #pragma unroll
        for (int ni = 0; ni < 4; ++ni) {
          const int col = n0 + wn + ni * 16 + l15;
          const float v = acc[mi][ni][reg];
          const int seg = col >> 10;
          const int cl  = col & 1023;
          const int hn  = cl >> 6, d = cl & 63;
          if (seg == 0) {
            if (t >= 512) {
              const size_t idx = (((size_t)bb * 16 + hn) * 512 + (t - 512)) * 64 + d;
              qwb[idx] = f2bf(v + rwbias[cl]);
              qrb[idx] = f2bf(v + rrbias[cl]);
            }
          } else if (seg == 1) {
            kbo[(((size_t)bb * 16 + hn) * 1024 + t) * 64 + d] = f2bf(v);
          } else {
            vto[(((size_t)bb * 16 + hn) * 64 + d) * 1024 + t] = f2bf(v);
          }
        }
      } else { // EP_RK
        #pragma unroll
        for (int ni = 0; ni < 4; ++ni) {
          const int col = n0 + wn + ni * 16 + l15;
          const int hn = col >> 6, d = col & 63;
          qwb[((size_t)hn * 1024 + row) * 64 + d] = f2bf(acc[mi][ni][reg]);
        }
      }
    }
  }
}

// Fused MFMA attention v5: split-KV inside the block, 128-reg budget.
// R1 post-mortem: __launch_bounds__(256,8) pinned the unified VGPR+AGPR
// budget to 64/wave; live state is ~100+ regs -> compiler spilled the
// accumulators to scratch (FETCH 35->654 MB, WRITE 43->790 MB, 2.5x
// regression). v5 keeps the split-KV structure (correctness verified in R1)
// but restores the (256,4) budget under which R0 compiled spill-free at
// VGPR=64. Residency is register-limited (~4 waves/SIMD) but the 2048-block
// grid gives the scheduler 8 blocks/CU of backfill and each wave's serial
// j-chain is half of R0's.
//   waves 0,1: j-tiles 0..3  (never masked: j<512 <= i+512 for all i)
//   waves 2,3: j-tiles 4..nsteps-1 (1..4 tiles, masked)
// Partials (m, l, unnormalized O) exchanged through p_lds recast as float.
__global__ __launch_bounds__(256, 4)
void fattn(const bf16* __restrict__ qw, const bf16* __restrict__ qr,
           const bf16* __restrict__ kb, const bf16* __restrict__ vT,
           const bf16* __restrict__ rk, bf16* __restrict__ avec)
{
  __shared__ __align__(16) unsigned short p_lds[4][16][136]; // 17408 B
  const int tid  = threadIdx.x;
  const int wave = tid >> 6, lane = tid & 63;
  const int quad = lane >> 4, l15 = lane & 15;
  // XCD-locality decode: bid = r + 8*(phi + 16*ib), pair = r + 8*phi
  const int bid = blockIdx.x;
  const int r_  = bid & 7;
  const int s_  = bid >> 3;
  const int phi = s_ & 15;
  const int ib  = s_ >> 4;            // i-block 0..15 (32 rows each)
  const int pr  = r_ + 8 * phi;       // (h,b) pair 0..127
  const int h   = pr & 15;
  const int b   = pr >> 4;
  const int i0  = ib * 32;
  const int w01   = wave & 1;         // which 16-row half of the i-block
  const int jhalf = wave >> 1;        // 0: j-tiles 0-3, 1: j-tiles 4..
  const int iw  = i0 + w01 * 16;
  const size_t bh = (size_t)b * 16 + h;
  const bf16* kp = kb + bh * 1024 * 64;
  const bf16* vp = vT + bh * 64 * 1024;
  const bf16* rp = rk + (size_t)h * 1024 * 64;

  frag8 aqw[2], aqr[2];
  {
    const bf16* r0 = qw + (bh * 512 + iw + l15) * 64 + quad * 8;
    aqw[0] = *(const frag8*)r0;
    aqw[1] = *(const frag8*)(r0 + 32);
    const bf16* r1 = qr + (bh * 512 + iw + l15) * 64 + quad * 8;
    aqr[0] = *(const frag8*)r1;
    aqr[1] = *(const frag8*)(r1 + 32);
  }

  f32x4 accO[4] = {};
  float m_run[4], l_run[4];
  #pragma unroll
  for (int rg = 0; rg < 4; ++rg) { m_run[rg] = -INFINITY; l_run[rg] = 0.f; }

  // per-wave j-tile range
  const int jt_beg = jhalf ? 4 : 0;
  const int jt_end = jhalf ? (((iw + 15 + 512) >> 7) + 1) : 4;
  const int offb   = 15 + l15 - quad * 4;

  for (int jt = jt_beg; jt < jt_end; ++jt) {
    const int j0 = jt << 7;
    // ---- AC scores (16 independent K loads + MFMAs) ----
    f32x4 accS[8] = {};
    #pragma unroll
    for (int ns = 0; ns < 8; ++ns) {
      const bf16* krow = kp + (size_t)(j0 + ns * 16 + l15) * 64 + quad * 8;
      frag8 bk0 = *(const frag8*)krow;
      frag8 bk1 = *(const frag8*)(krow + 32);
      accS[ns] = __builtin_amdgcn_mfma_f32_16x16x32_bf16(aqw[0], bk0, accS[ns], 0,0,0);
      accS[ns] = __builtin_amdgcn_mfma_f32_16x16x32_bf16(aqw[1], bk1, accS[ns], 0,0,0);
    }
    // ---- BD: all 9 p-subtiles materialized (independent loads + MFMAs) ----
    const int pbase = 496 + j0 - iw;
    f32x4 bsub[9];
    #pragma unroll
    for (int ns = 0; ns < 9; ++ns) {
      const int prow = min(pbase + ns * 16 + l15, 1023);
      const bf16* rrow = rp + (size_t)prow * 64 + quad * 8;
      frag8 br0 = *(const frag8*)rrow;
      frag8 br1 = *(const frag8*)(rrow + 32);
      f32x4 z = {};
      z = __builtin_amdgcn_mfma_f32_16x16x32_bf16(aqr[0], br0, z, 0,0,0);
      bsub[ns] = __builtin_amdgcn_mfma_f32_16x16x32_bf16(aqr[1], br1, z, 0,0,0);
    }
    // ---- in-register shift + combine + mask + tile max ----
    float tmax[4] = {-INFINITY, -INFINITY, -INFINITY, -INFINITY};
    #pragma unroll
    for (int ns = 0; ns < 8; ++ns) {
      #pragma unroll
      for (int rg = 0; rg < 4; ++rg) {
        const int o    = offb - rg;                 // [0,30]
        const int srcl = (quad << 4) | (o & 15);
        const float lo = __shfl(bsub[ns][rg],     srcl, 64);
        const float hi = __shfl(bsub[ns + 1][rg], srcl, 64);
        const float bd = (o & 16) ? hi : lo;
        float s = (accS[ns][rg] + bd) * 0.125f;
        if (jhalf) {  // low half (j<512) is never masked: j <= 511 < i+512
          const int j = j0 + ns * 16 + l15;
          s = (j > iw + quad * 4 + rg + 512) ? -INFINITY : s;
        }
        accS[ns][rg] = s;
        tmax[rg] = fmaxf(tmax[rg], s);
      }
    }
    #pragma unroll
    for (int off = 1; off < 16; off <<= 1)
      #pragma unroll
      for (int rg = 0; rg < 4; ++rg)
        tmax[rg] = fmaxf(tmax[rg], __shfl_xor(tmax[rg], off, 64));
    // ---- online softmax update ----
    float alpha[4], tsum[4] = {0.f, 0.f, 0.f, 0.f};
    #pragma unroll
    for (int rg = 0; rg < 4; ++rg) {
      const float nm = fmaxf(m_run[rg], tmax[rg]);
      alpha[rg] = __expf(m_run[rg] - nm);
      m_run[rg] = nm;
    }
    #pragma unroll
    for (int ns = 0; ns < 8; ++ns)
      #pragma unroll
      for (int rg = 0; rg < 4; ++rg) {
        const int rl = quad * 4 + rg;
        const float pv = __expf(accS[ns][rg] - m_run[rg]);
        tsum[rg] += pv;
        p_lds[wave][rl][ns * 16 + l15] = bfbits(pv);
      }
    #pragma unroll
    for (int off = 1; off < 16; off <<= 1)
      #pragma unroll
      for (int rg = 0; rg < 4; ++rg)
        tsum[rg] += __shfl_xor(tsum[rg], off, 64);
    #pragma unroll
    for (int rg = 0; rg < 4; ++rg)
      l_run[rg] = l_run[rg] * alpha[rg] + tsum[rg];
    #pragma unroll
    for (int nd = 0; nd < 4; ++nd)
      #pragma unroll
      for (int rg = 0; rg < 4; ++rg)
        accO[nd][rg] *= alpha[rg];
    __builtin_amdgcn_wave_barrier();
    // ---- PV ----
    #pragma unroll
    for (int ks = 0; ks < 4; ++ks) {
      frag8 ap = *(const frag8*)&p_lds[wave][l15][ks * 32 + quad * 8];
      #pragma unroll
      for (int nd = 0; nd < 4; ++nd) {
        const bf16* vrow = vp + (size_t)(nd * 16 + l15) * 1024 + j0 + ks * 32 + quad * 8;
        frag8 bv = *(const frag8*)vrow;
        accO[nd] = __builtin_amdgcn_mfma_f32_16x16x32_bf16(ap, bv, accO[nd], 0,0,0);
      }
    }
    __builtin_amdgcn_wave_barrier();
  }

  // ---- cross-wave combine: wave w (j-tiles 0-3) + wave w+2 (j-tiles 4+) ----
  // Exchange through p_lds recast as float: 4352 floats total, 1088 per wave
  // region; each upper wave needs 1024 (O) + 32 (m,l) = 1056 floats.
  float* xch = (float*)&p_lds[0][0][0];
  if (jhalf) {
    float* mybase = xch + wave * 1088;
    #pragma unroll
    for (int rg = 0; rg < 4; ++rg) {
      const int row = quad * 4 + rg;
      #pragma unroll
      for (int nd = 0; nd < 4; ++nd)
        mybase[row * 64 + nd * 16 + l15] = accO[nd][rg];
      if (l15 == 0) {
        mybase[1024 + row * 2]     = m_run[rg];
        mybase[1024 + row * 2 + 1] = l_run[rg];
      }
    }
  }
  __syncthreads();
  if (!jhalf) {
    const float* pb = xch + (wave + 2) * 1088;
    #pragma unroll
    for (int rg = 0; rg < 4; ++rg) {
      const int row = quad * 4 + rg;
      const float mB = pb[1024 + row * 2];
      const float lB = pb[1024 + row * 2 + 1];
      const float m  = fmaxf(m_run[rg], mB);
      const float aA = __expf(m_run[rg] - m);
      const float aB = __expf(mB - m);
      const float inv = 1.f / (l_run[rg] * aA + lB * aB);
      const int i = iw + row;
      #pragma unroll
      for (int nd = 0; nd < 4; ++nd) {
        const int d = nd * 16 + l15;
        const float oB = pb[row * 64 + d];
        avec[((size_t)i * 8 + b) * 1024 + h * 64 + d] =
            f2bf((accO[nd][rg] * aA + oB * aB) * inv);
      }
    }
  }
}

// row LayerNorm over 1024 cols; one block per row.
template<typename TOUT>
__global__ __launch_bounds__(256)
void ln_kernel(const bf16* __restrict__ x, const float* __restrict__ g,
               const float* __restrict__ be, TOUT* __restrict__ out)
{
  __shared__ float red0[4];
  __shared__ float red1[4];
  const int row = blockIdx.x;
  const int tid = threadIdx.x;
  const bf16* xr = x + (size_t)row * 1024;
  ushort4 u = *(const ushort4*)(xr + (tid << 2));
  const float v0 = u16f(u.x), v1 = u16f(u.y), v2 = u16f(u.z), v3 = u16f(u.w);
  float sum = v0 + v1 + v2 + v3;
  #pragma unroll
  for (int off = 1; off < 64; off <<= 1) sum += __shfl_xor(sum, off, 64);
  if ((tid & 63) == 0) red0[tid >> 6] = sum;
  __syncthreads();
  const float mu = (red0[0] + red0[1] + red0[2] + red0[3]) * (1.f / 1024.f);
  const float d0 = v0 - mu, d1 = v1 - mu, d2 = v2 - mu, d3 = v3 - mu;
  float sq = d0*d0 + d1*d1 + d2*d2 + d3*d3;
  #pragma unroll
  for (int off = 1; off < 64; off <<= 1) sq += __shfl_xor(sq, off, 64);
  if ((tid & 63) == 0) red1[tid >> 6] = sq;
  __syncthreads();
  const float var = (red1[0] + red1[1] + red1[2] + red1[3]) * (1.f / 1024.f);
  const float inv = 1.f / sqrtf(var + 1e-5f);
  const int c = tid << 2;
  float4 ug = *(const float4*)(g + c);
  float4 ub = *(const float4*)(be + c);
  TOUT* orow = out + (size_t)row * 1024;
  orow[c+0] = (TOUT)(d0 * inv * ug.x + ub.x);
  orow[c+1] = (TOUT)(d1 * inv * ug.y + ub.y);
  orow[c+2] = (TOUT)(d2 * inv * ug.z + ub.z);
  orow[c+3] = (TOUT)(d3 * inv * ug.w + ub.w);
}

extern "C" void kernel_launch(void* const* d_in, const int* in_sizes, int n_in,
                              void* d_out, int out_size, void* d_ws, size_t ws_size,
                              hipStream_t stream)
{
  const float* w    = (const float*)d_in[0];
  const float* r    = (const float*)d_in[1];
  const float* rwb  = (const float*)d_in[2];
  const float* rrb  = (const float*)d_in[3];
  const float* mems = (const float*)d_in[4];
  // d_in[5] = attn_mask: deterministic (j > i + 512), computed in-kernel
  const float* Wqkv = (const float*)d_in[6];
  const float* Wr   = (const float*)d_in[7];
  const float* Wo   = (const float*)d_in[8];
  const float* ln1g = (const float*)d_in[9];
  const float* ln1b = (const float*)d_in[10];
  const float* W1   = (const float*)d_in[11];
  const float* b1   = (const float*)d_in[12];
  const float* W2   = (const float*)d_in[13];
  const float* b2   = (const float*)d_in[14];
  const float* ln2g = (const float*)d_in[15];
  const float* ln2b = (const float*)d_in[16];

  // Workspace (bf16), liveness-aliased, peak 94 MiB (layout unchanged from R5)
  const size_t MB = 1u << 20;
  char* p = (char*)d_ws;
  bf16* catb  = (bf16*)(p +  0 * MB);
  bf16* wqkvb = (bf16*)(p + 16 * MB);
  bf16* wrb   = (bf16*)(p + 22 * MB);
  bf16* wob   = (bf16*)(p + 24 * MB);
  bf16* w1b   = (bf16*)(p + 26 * MB);
  bf16* w2b   = (bf16*)(p + 34 * MB);
  bf16* qwbuf = (bf16*)(p + 42 * MB);
  bf16* qrbuf = (bf16*)(p + 50 * MB);
  bf16* kbuf  = (bf16*)(p + 58 * MB);
  bf16* vTbuf = (bf16*)(p + 74 * MB);
  bf16* rkbuf = (bf16*)(p + 90 * MB);
  bf16* rb    = (bf16*)(p + 92 * MB);
  bf16* avec  = (bf16*)(p +  0 * MB);
  bf16* x1    = (bf16*)(p +  8 * MB);
  bf16* o1    = (bf16*)(p + 42 * MB);
  bf16* x2    = (bf16*)(p + 50 * MB);
  bf16* h     = (bf16*)(p + 58 * MB);

  dim3 blk(256);
  // 0. fp32 -> bf16 converts (one batched launch)
  {
    CvtArgs a;
    const int n4w = (4096 * 1024) / 4, n4r = (1024 * 1024) / 4,
              n4qkv = (3072 * 1024) / 4;
    a.src[0] = mems; a.dst[0] = catb;                        int n0_ = n4w;
    a.src[1] = w;    a.dst[1] = catb + (size_t)4096 * 1024;  int n1_ = n4w;
    a.src[2] = r;    a.dst[2] = rb;                          int n2_ = n4r;
    a.src[3] = Wqkv; a.dst[3] = wqkvb;                       int n3_ = n4qkv;
    a.src[4] = Wr;   a.dst[4] = wrb;                         int n4_ = n4r;
    a.src[5] = Wo;   a.dst[5] = wob;                         int n5_ = n4r;
    a.src[6] = W1;   a.dst[6] = w1b;                         int n6_ = n4w;
    a.src[7] = W2;   a.dst[7] = w2b;                         int n7_ = n4w;
    const int ns_[8] = {n0_, n1_, n2_, n3_, n4_, n5_, n6_, n7_};
    a.cum[0] = 0;
    for (int s2 = 0; s2 < 8; ++s2) a.cum[s2 + 1] = a.cum[s2] + ns_[s2];
    cvt8<<<dim3((a.cum[8] + 255) / 256), blk, 0, stream>>>(a);
  }

  // 1. heads = cat @ Wqkv^T -> scatter qw/qr (biases added), kb, vT
  mgemm<float><<<dim3(24, 64), blk, 0, stream>>>(catb, wqkvb, nullptr, (const float*)nullptr,
        nullptr, qwbuf, qrbuf, kbuf, vTbuf, rwb, rrb, 8192, 3072, 1024, EP_QKV, 0);
  // 2. rk = r @ Wr^T -> (h,p,d)
  mgemm<float><<<dim3(8, 8), blk, 0, stream>>>(rb, wrb, nullptr, (const float*)nullptr,
        nullptr, rkbuf, nullptr, nullptr, nullptr, nullptr, nullptr,
        1024, 1024, 1024, EP_RK, 0);
  // 3. fused MFMA attention -> avec (2048 blocks, split-KV, XCD-swizzled)
  fattn<<<dim3(2048), blk, 0, stream>>>(qwbuf, qrbuf, kbuf, vTbuf, rkbuf, avec);
  // 4. x1 = w + avec @ Wo^T
  mgemm<float><<<dim3(8, 32), blk, 0, stream>>>(avec, wob, nullptr, w,
        x1, nullptr, nullptr, nullptr, nullptr, nullptr, nullptr,
        4096, 1024, 1024, EP_PLAIN, 0);
  // 5. out1 = LN(x1)
  ln_kernel<bf16><<<dim3(4096), blk, 0, stream>>>(x1, ln1g, ln1b, o1);
  // 6. h = relu(out1 @ W1^T + b1)
  mgemm<float><<<dim3(32, 32), blk, 0, stream>>>(o1, w1b, b1, (const float*)nullptr,
        h, nullptr, nullptr, nullptr, nullptr, nullptr, nullptr,
        4096, 4096, 1024, EP_PLAIN, 1);
  // 7. x2 = out1 + h @ W2^T + b2
  mgemm<bf16><<<dim3(8, 32), blk, 0, stream>>>(h, w2b, b2, o1,
        x2, nullptr, nullptr, nullptr, nullptr, nullptr, nullptr,
        4096, 1024, 4096, EP_PLAIN, 0);
  // 8. out = LN(x2) -> fp32
  ln_kernel<float><<<dim3(4096), blk, 0, stream>>>(x2, ln2g, ln2b, (float*)d_out);
}

// Round 3
// 626.862 us; speedup vs baseline: 1.5713x; 1.1070x over previous
//
#include <hip/hip_runtime.h>
#include <hip/hip_bf16.h>

typedef __hip_bfloat16 bf16;

typedef __attribute__((ext_vector_type(8))) short frag8;
typedef __attribute__((ext_vector_type(4))) float f32x4;

__device__ __forceinline__ bf16 f2bf(float f) { return __float2bfloat16(f); }

__device__ __forceinline__ float u16f(unsigned short u) {
  union { unsigned int i; float f; } c; c.i = ((unsigned int)u) << 16; return c.f;
}
__device__ __forceinline__ unsigned short bfbits(float f) {
  union { bf16 b; unsigned short u; } c; c.b = __float2bfloat16(f); return c.u;
}
__device__ __forceinline__ float tof(float x) { return x; }
__device__ __forceinline__ float tof(bf16 x)  { return __bfloat162float(x); }

// async 16B global->LDS copy (m97 pattern)
__device__ __forceinline__ void gload_lds16(const bf16* g, short* l) {
  __builtin_amdgcn_global_load_lds(
      (const __attribute__((address_space(1))) void*)g,
      (__attribute__((address_space(3))) void*)l, 16, 0, 0);
}

#define EP_PLAIN 0
#define EP_QKV   1
#define EP_RK    2

// batched fp32 -> bf16 convert: 8 segments in one launch
struct CvtArgs {
  const float* src[8];
  bf16* dst[8];
  int cum[9];          // cumulative n4 boundaries
};
__global__ __launch_bounds__(256)
void cvt8(CvtArgs a)
{
  const int i = blockIdx.x * 256 + threadIdx.x;
  if (i >= a.cum[8]) return;
  int seg = 7;
  #pragma unroll
  for (int s2 = 6; s2 >= 0; --s2) if (i < a.cum[s2 + 1]) seg = s2;
  const int o = i - a.cum[seg];
  float4 v = ((const float4*)a.src[seg])[o];
  ushort4 u;
  u.x = bfbits(v.x); u.y = bfbits(v.y); u.z = bfbits(v.z); u.w = bfbits(v.w);
  ((ushort4*)a.dst[seg])[o] = u;
}

// MFMA GEMM: C[M,N] = A[M,K] @ W[N,K]^T, bf16 in, fp32 accum.
// 128x128 tile, BK=32, 4 waves (2x2), global_load_lds staging (R6).
template<typename TRES>
__global__ __launch_bounds__(256)
void mgemm(const bf16* __restrict__ A, const bf16* __restrict__ W,
           const float* __restrict__ bias, const TRES* __restrict__ res,
           bf16* __restrict__ out,
           bf16* __restrict__ qwb, bf16* __restrict__ qrb,
           bf16* __restrict__ kbo, bf16* __restrict__ vto,
           const float* __restrict__ rwbias, const float* __restrict__ rrbias,
           int M, int N, int K, int mode, int relu)
{
  __shared__ __align__(16) short sA[128 * 32];
  __shared__ __align__(16) short sB[128 * 32];
  const int tid  = threadIdx.x;
  const int lane = tid & 63;
  const int wave = tid >> 6;
  const int quad = lane >> 4;
  const int l15  = lane & 15;
  const int m0 = blockIdx.y * 128;
  const int n0 = blockIdx.x * 128;
  const int wm = (wave >> 1) * 64;
  const int wn = (wave & 1) * 64;

  const int lr = tid >> 2;
  const int lc = (tid & 3) << 3;

  const bf16* aptr0 = A + (size_t)(m0 + lr) * K + lc;
  const bf16* aptr1 = aptr0 + (size_t)64 * K;
  const bf16* wptr0 = W + (size_t)(n0 + lr) * K + lc;
  const bf16* wptr1 = wptr0 + (size_t)64 * K;

  short* ldsA0 = &sA[wave * 512];
  short* ldsA1 = &sA[2048 + wave * 512];
  short* ldsB0 = &sB[wave * 512];
  short* ldsB1 = &sB[2048 + wave * 512];

  f32x4 acc[4][4] = {};

  for (int kk = 0; kk < K; kk += 32) {
    __syncthreads();
    gload_lds16(aptr0 + kk, ldsA0);
    gload_lds16(aptr1 + kk, ldsA1);
    gload_lds16(wptr0 + kk, ldsB0);
    gload_lds16(wptr1 + kk, ldsB1);
    __syncthreads();
    frag8 af[4], bfr[4];
    #pragma unroll
    for (int t = 0; t < 4; ++t) {
      af[t]  = *(const frag8*)&sA[(wm + t * 16 + l15) * 32 + quad * 8];
      bfr[t] = *(const frag8*)&sB[(wn + t * 16 + l15) * 32 + quad * 8];
    }
    #pragma unroll
    for (int mi = 0; mi < 4; ++mi)
      #pragma unroll
      for (int ni = 0; ni < 4; ++ni)
        acc[mi][ni] = __builtin_amdgcn_mfma_f32_16x16x32_bf16(
            af[mi], bfr[ni], acc[mi][ni], 0, 0, 0);
  }

  #pragma unroll
  for (int mi = 0; mi < 4; ++mi) {
    #pragma unroll
    for (int reg = 0; reg < 4; ++reg) {
      const int row = m0 + wm + mi * 16 + quad * 4 + reg;
      if (mode == EP_PLAIN) {
        bf16* orow = out + (size_t)row * N;
        const TRES* rrow = res ? res + (size_t)row * N : nullptr;
        #pragma unroll
        for (int ni = 0; ni < 4; ++ni) {
          const int col = n0 + wn + ni * 16 + l15;
          float v = acc[mi][ni][reg];
          if (bias) v += bias[col];
          if (relu) v = fmaxf(v, 0.f);
          if (rrow) v += tof(rrow[col]);
          orow[col] = f2bf(v);
        }
      } else if (mode == EP_QKV) {
        const int t = row >> 3, bb = row & 7;
        #pragma unroll
        for (int ni = 0; ni < 4; ++ni) {
          const int col = n0 + wn + ni * 16 + l15;
          const float v = acc[mi][ni][reg];
          const int seg = col >> 10;
          const int cl  = col & 1023;
          const int hn  = cl >> 6, d = cl & 63;
          if (seg == 0) {
            if (t >= 512) {
              const size_t idx = (((size_t)bb * 16 + hn) * 512 + (t - 512)) * 64 + d;
              qwb[idx] = f2bf(v + rwbias[cl]);
              qrb[idx] = f2bf(v + rrbias[cl]);
            }
          } else if (seg == 1) {
            kbo[(((size_t)bb * 16 + hn) * 1024 + t) * 64 + d] = f2bf(v);
          } else {
            vto[(((size_t)bb * 16 + hn) * 64 + d) * 1024 + t] = f2bf(v);
          }
        }
      } else { // EP_RK
        #pragma unroll
        for (int ni = 0; ni < 4; ++ni) {
          const int col = n0 + wn + ni * 16 + l15;
          const int hn = col >> 6, d = col & 63;
          qwb[((size_t)hn * 1024 + row) * 64 + d] = f2bf(acc[mi][ni][reg]);
        }
      }
    }
  }
}

// Fused MFMA attention v6: R0 structure (1024 blocks, 4 waves x 16 rows) +
// LDS staging of K and V tiles shared by all 4 waves.
// R2 post-mortem: fattn is L2/L3-BW-bound: 50 global 16B frag-loads per
// wave-tile = 1.36 GB/dispatch = 7.9 TB/s demand; per-XCD K/V working set
// (16 pairs x 256 KB) ~= L2 size, so re-reads stream from L3 (~2-3 TB/s).
// All 4 waves of a block read IDENTICAL K and V rows -> stage each j-tile's
// K (128x64) and V (64x128) in LDS once per block (traffic /4). rk stays
// global: per-XCD rk footprint is 2 heads x 128 KB = L2-resident.
// Swizzle (rule #21): gload_lds writes linearly, so apply the bank XOR
// ((row&7)<<4 on the byte offset) to the GLOBAL source address and the same
// XOR on the ds_read side; 16-way conflict -> 2-way (free).
// Schedule per tile: BD (global rk) first to overlap staging latency;
// barrier; AC from sK; shift+softmax; PV from sV; barrier; stage next tile.
// nsteps is block-uniform (max over waves); extra tiles for low waves are
// fully masked -> exp()=0, inert. LDS 16+16+17 KB = 49 KB -> 3 blocks/CU,
// so (256,3) launch bounds are free and give a 170-reg budget (no spills).
__global__ __launch_bounds__(256, 3)
void fattn(const bf16* __restrict__ qw, const bf16* __restrict__ qr,
           const bf16* __restrict__ kb, const bf16* __restrict__ vT,
           const bf16* __restrict__ rk, bf16* __restrict__ avec)
{
  __shared__ __align__(16) short sK[8192];   // 128 j x 64 d bf16, swizzled (16 KB)
  __shared__ __align__(16) short sV[8192];   // 64 d x 128 j bf16, swizzled (16 KB)
  __shared__ __align__(16) unsigned short p_lds[4][16][136]; // 17408 B
  const int tid  = threadIdx.x;
  const int wave = tid >> 6, lane = tid & 63;
  const int quad = lane >> 4, l15 = lane & 15;
  // XCD-locality decode: bid = r + 8*(phi + 16*it), pair = r + 8*phi
  const int bid = blockIdx.x;
  const int r_  = bid & 7;
  const int s_  = bid >> 3;
  const int phi = s_ & 15;
  const int it  = s_ >> 4;            // i-tile 0..7
  const int pr  = r_ + 8 * phi;       // (h,b) pair 0..127
  const int h   = pr & 15;
  const int b   = pr >> 4;
  const int i0  = it * 64;
  const int iw  = i0 + wave * 16;
  const size_t bh = (size_t)b * 16 + h;
  const bf16* kp = kb + bh * 1024 * 64;
  const bf16* vp = vT + bh * 64 * 1024;
  const bf16* rp = rk + (size_t)h * 1024 * 64;

  frag8 aqw[2], aqr[2];
  {
    const bf16* r0 = qw + (bh * 512 + iw + l15) * 64 + quad * 8;
    aqw[0] = *(const frag8*)r0;
    aqw[1] = *(const frag8*)(r0 + 32);
    const bf16* r1 = qr + (bh * 512 + iw + l15) * 64 + quad * 8;
    aqr[0] = *(const frag8*)r1;
    aqr[1] = *(const frag8*)(r1 + 32);
  }

  f32x4 accO[4] = {};
  float m_run[4], l_run[4];
  #pragma unroll
  for (int rg = 0; rg < 4; ++rg) { m_run[rg] = -INFINITY; l_run[rg] = 0.f; }

  // block-uniform step count (i_last = i0+63); low waves' extra tiles are
  // fully masked (s=-inf -> pv=0 -> no contribution)
  const int nsteps = ((i0 + 63 + 512) >> 7) + 1;
  const int offb   = 15 + l15 - quad * 4;

  // stage j-tile [j0s, j0s+128) of K and V into sK/sV.
  // Linear LDS write (gload_lds), inverse-swizzled global source:
  //   content(sK[Lb]) = K[Lb ^ ((row&7)<<4)], row = Lb>>7  (128 B rows)
  //   content(sV[Lb]) = V[Lb ^ ((row&7)<<4)], row = Lb>>8  (256 B rows)
  auto stage = [&](int j0s) {
    #pragma unroll
    for (int c = 0; c < 4; ++c) {
      const int Lb  = c * 4096 + tid * 16;
      short* ldst   = (short*)((char*)sK + (c * 4096 + wave * 1024));
      short* ldstV  = (short*)((char*)sV + (c * 4096 + wave * 1024));
      const int rK  = Lb >> 7;
      const int UK  = Lb ^ ((rK & 7) << 4);
      gload_lds16((const bf16*)((const char*)kp + (size_t)j0s * 128 + UK), ldst);
      const int rV  = Lb >> 8;
      const int UV  = Lb ^ ((rV & 7) << 4);
      const int cbV = UV & 255;      // byte-in-row (row preserved by XOR)
      gload_lds16((const bf16*)((const char*)vp + (size_t)rV * 2048 + (size_t)j0s * 2 + cbV),
                  ldstV);
    }
  };
  stage(0);

  for (int jt = 0; jt < nsteps; ++jt) {
    const int j0 = jt << 7;
    // ---- BD first: global rk loads (L2-resident) overlap K/V staging ----
    const int pbase = 496 + j0 - iw;
    f32x4 bsub[9];
    #pragma unroll
    for (int ns = 0; ns < 9; ++ns) {
      const int prow = min(pbase + ns * 16 + l15, 1023);
      const bf16* rrow = rp + (size_t)prow * 64 + quad * 8;
      frag8 br0 = *(const frag8*)rrow;
      frag8 br1 = *(const frag8*)(rrow + 32);
      f32x4 z = {};
      z = __builtin_amdgcn_mfma_f32_16x16x32_bf16(aqr[0], br0, z, 0,0,0);
      bsub[ns] = __builtin_amdgcn_mfma_f32_16x16x32_bf16(aqr[1], br1, z, 0,0,0);
    }
    __syncthreads();   // sK/sV for this tile are resident
    // ---- AC scores from sK (swizzled ds_read_b128) ----
    f32x4 accS[8] = {};
    #pragma unroll
    for (int ns = 0; ns < 8; ++ns) {
      const int row = ns * 16 + l15;
      const int sw  = (row & 7) << 4;
      frag8 bk0 = *(const frag8*)((const char*)sK + ((row * 128 + quad * 16) ^ sw));
      frag8 bk1 = *(const frag8*)((const char*)sK + ((row * 128 + 64 + quad * 16) ^ sw));
      accS[ns] = __builtin_amdgcn_mfma_f32_16x16x32_bf16(aqw[0], bk0, accS[ns], 0,0,0);
      accS[ns] = __builtin_amdgcn_mfma_f32_16x16x32_bf16(aqw[1], bk1, accS[ns], 0,0,0);
    }
    // ---- in-register shift + combine + mask + tile max ----
    float tmax[4] = {-INFINITY, -INFINITY, -INFINITY, -INFINITY};
    #pragma unroll
    for (int ns = 0; ns < 8; ++ns) {
      #pragma unroll
      for (int rg = 0; rg < 4; ++rg) {
        const int o    = offb - rg;                 // [0,30]
        const int srcl = (quad << 4) | (o & 15);
        const float lo = __shfl(bsub[ns][rg],     srcl, 64);
        const float hi = __shfl(bsub[ns + 1][rg], srcl, 64);
        const float bd = (o & 16) ? hi : lo;
        float s = (accS[ns][rg] + bd) * 0.125f;
        const int j = j0 + ns * 16 + l15;
        s = (j > iw + quad * 4 + rg + 512) ? -INFINITY : s;
        accS[ns][rg] = s;
        tmax[rg] = fmaxf(tmax[rg], s);
      }
    }
    #pragma unroll
    for (int off = 1; off < 16; off <<= 1)
      #pragma unroll
      for (int rg = 0; rg < 4; ++rg)
        tmax[rg] = fmaxf(tmax[rg], __shfl_xor(tmax[rg], off, 64));
    // ---- online softmax update ----
    float alpha[4], tsum[4] = {0.f, 0.f, 0.f, 0.f};
    #pragma unroll
    for (int rg = 0; rg < 4; ++rg) {
      const float nm = fmaxf(m_run[rg], tmax[rg]);
      alpha[rg] = __expf(m_run[rg] - nm);
      m_run[rg] = nm;
    }
    #pragma unroll
    for (int ns = 0; ns < 8; ++ns)
      #pragma unroll
      for (int rg = 0; rg < 4; ++rg) {
        const int rl = quad * 4 + rg;
        const float pv = __expf(accS[ns][rg] - m_run[rg]);
        tsum[rg] += pv;
        p_lds[wave][rl][ns * 16 + l15] = bfbits(pv);
      }
    #pragma unroll
    for (int off = 1; off < 16; off <<= 1)
      #pragma unroll
      for (int rg = 0; rg < 4; ++rg)
        tsum[rg] += __shfl_xor(tsum[rg], off, 64);
    #pragma unroll
    for (int rg = 0; rg < 4; ++rg)
      l_run[rg] = l_run[rg] * alpha[rg] + tsum[rg];
    #pragma unroll
    for (int nd = 0; nd < 4; ++nd)
      #pragma unroll
      for (int rg = 0; rg < 4; ++rg)
        accO[nd][rg] *= alpha[rg];
    __builtin_amdgcn_wave_barrier();
    // ---- PV from sV (swizzled ds_read_b128) ----
    #pragma unroll
    for (int ks = 0; ks < 4; ++ks) {
      frag8 ap = *(const frag8*)&p_lds[wave][l15][ks * 32 + quad * 8];
      #pragma unroll
      for (int nd = 0; nd < 4; ++nd) {
        const int d = nd * 16 + l15;
        frag8 bv = *(const frag8*)((const char*)sV +
                    ((d * 256 + ks * 64 + quad * 16) ^ ((d & 7) << 4)));
        accO[nd] = __builtin_amdgcn_mfma_f32_16x16x32_bf16(ap, bv, accO[nd], 0,0,0);
      }
    }
    __builtin_amdgcn_wave_barrier();
    __syncthreads();   // all waves done reading sK/sV
    if (jt + 1 < nsteps) stage((jt + 1) << 7);
  }

  #pragma unroll
  for (int rg = 0; rg < 4; ++rg) {
    const int i = iw + quad * 4 + rg;
    const float inv = 1.f / l_run[rg];
    #pragma unroll
    for (int nd = 0; nd < 4; ++nd) {
      const int d = nd * 16 + l15;
      avec[((size_t)i * 8 + b) * 1024 + h * 64 + d] = f2bf(accO[nd][rg] * inv);
    }
  }
}

// row LayerNorm over 1024 cols; one block per row.
template<typename TOUT>
__global__ __launch_bounds__(256)
void ln_kernel(const bf16* __restrict__ x, const float* __restrict__ g,
               const float* __restrict__ be, TOUT* __restrict__ out)
{
  __shared__ float red0[4];
  __shared__ float red1[4];
  const int row = blockIdx.x;
  const int tid = threadIdx.x;
  const bf16* xr = x + (size_t)row * 1024;
  ushort4 u = *(const ushort4*)(xr + (tid << 2));
  const float v0 = u16f(u.x), v1 = u16f(u.y), v2 = u16f(u.z), v3 = u16f(u.w);
  float sum = v0 + v1 + v2 + v3;
  #pragma unroll
  for (int off = 1; off < 64; off <<= 1) sum += __shfl_xor(sum, off, 64);
  if ((tid & 63) == 0) red0[tid >> 6] = sum;
  __syncthreads();
  const float mu = (red0[0] + red0[1] + red0[2] + red0[3]) * (1.f / 1024.f);
  const float d0 = v0 - mu, d1 = v1 - mu, d2 = v2 - mu, d3 = v3 - mu;
  float sq = d0*d0 + d1*d1 + d2*d2 + d3*d3;
  #pragma unroll
  for (int off = 1; off < 64; off <<= 1) sq += __shfl_xor(sq, off, 64);
  if ((tid & 63) == 0) red1[tid >> 6] = sq;
  __syncthreads();
  const float var = (red1[0] + red1[1] + red1[2] + red1[3]) * (1.f / 1024.f);
  const float inv = 1.f / sqrtf(var + 1e-5f);
  const int c = tid << 2;
  float4 ug = *(const float4*)(g + c);
  float4 ub = *(const float4*)(be + c);
  TOUT* orow = out + (size_t)row * 1024;
  orow[c+0] = (TOUT)(d0 * inv * ug.x + ub.x);
  orow[c+1] = (TOUT)(d1 * inv * ug.y + ub.y);
  orow[c+2] = (TOUT)(d2 * inv * ug.z + ub.z);
  orow[c+3] = (TOUT)(d3 * inv * ug.w + ub.w);
}

extern "C" void kernel_launch(void* const* d_in, const int* in_sizes, int n_in,
                              void* d_out, int out_size, void* d_ws, size_t ws_size,
                              hipStream_t stream)
{
  const float* w    = (const float*)d_in[0];
  const float* r    = (const float*)d_in[1];
  const float* rwb  = (const float*)d_in[2];
  const float* rrb  = (const float*)d_in[3];
  const float* mems = (const float*)d_in[4];
  // d_in[5] = attn_mask: deterministic (j > i + 512), computed in-kernel
  const float* Wqkv = (const float*)d_in[6];
  const float* Wr   = (const float*)d_in[7];
  const float* Wo   = (const float*)d_in[8];
  const float* ln1g = (const float*)d_in[9];
  const float* ln1b = (const float*)d_in[10];
  const float* W1   = (const float*)d_in[11];
  const float* b1   = (const float*)d_in[12];
  const float* W2   = (const float*)d_in[13];
  const float* b2   = (const float*)d_in[14];
  const float* ln2g = (const float*)d_in[15];
  const float* ln2b = (const float*)d_in[16];

  // Workspace (bf16), liveness-aliased, peak 94 MiB (layout unchanged from R5)
  const size_t MB = 1u << 20;
  char* p = (char*)d_ws;
  bf16* catb  = (bf16*)(p +  0 * MB);
  bf16* wqkvb = (bf16*)(p + 16 * MB);
  bf16* wrb   = (bf16*)(p + 22 * MB);
  bf16* wob   = (bf16*)(p + 24 * MB);
  bf16* w1b   = (bf16*)(p + 26 * MB);
  bf16* w2b   = (bf16*)(p + 34 * MB);
  bf16* qwbuf = (bf16*)(p + 42 * MB);
  bf16* qrbuf = (bf16*)(p + 50 * MB);
  bf16* kbuf  = (bf16*)(p + 58 * MB);
  bf16* vTbuf = (bf16*)(p + 74 * MB);
  bf16* rkbuf = (bf16*)(p + 90 * MB);
  bf16* rb    = (bf16*)(p + 92 * MB);
  bf16* avec  = (bf16*)(p +  0 * MB);
  bf16* x1    = (bf16*)(p +  8 * MB);
  bf16* o1    = (bf16*)(p + 42 * MB);
  bf16* x2    = (bf16*)(p + 50 * MB);
  bf16* h     = (bf16*)(p + 58 * MB);

  dim3 blk(256);
  // 0. fp32 -> bf16 converts (one batched launch)
  {
    CvtArgs a;
    const int n4w = (4096 * 1024) / 4, n4r = (1024 * 1024) / 4,
              n4qkv = (3072 * 1024) / 4;
    a.src[0] = mems; a.dst[0] = catb;                        int n0_ = n4w;
    a.src[1] = w;    a.dst[1] = catb + (size_t)4096 * 1024;  int n1_ = n4w;
    a.src[2] = r;    a.dst[2] = rb;                          int n2_ = n4r;
    a.src[3] = Wqkv; a.dst[3] = wqkvb;                       int n3_ = n4qkv;
    a.src[4] = Wr;   a.dst[4] = wrb;                         int n4_ = n4r;
    a.src[5] = Wo;   a.dst[5] = wob;                         int n5_ = n4r;
    a.src[6] = W1;   a.dst[6] = w1b;                         int n6_ = n4w;
    a.src[7] = W2;   a.dst[7] = w2b;                         int n7_ = n4w;
    const int ns_[8] = {n0_, n1_, n2_, n3_, n4_, n5_, n6_, n7_};
    a.cum[0] = 0;
    for (int s2 = 0; s2 < 8; ++s2) a.cum[s2 + 1] = a.cum[s2] + ns_[s2];
    cvt8<<<dim3((a.cum[8] + 255) / 256), blk, 0, stream>>>(a);
  }

  // 1. heads = cat @ Wqkv^T -> scatter qw/qr (biases added), kb, vT
  mgemm<float><<<dim3(24, 64), blk, 0, stream>>>(catb, wqkvb, nullptr, (const float*)nullptr,
        nullptr, qwbuf, qrbuf, kbuf, vTbuf, rwb, rrb, 8192, 3072, 1024, EP_QKV, 0);
  // 2. rk = r @ Wr^T -> (h,p,d)
  mgemm<float><<<dim3(8, 8), blk, 0, stream>>>(rb, wrb, nullptr, (const float*)nullptr,
        nullptr, rkbuf, nullptr, nullptr, nullptr, nullptr, nullptr,
        1024, 1024, 1024, EP_RK, 0);
  // 3. fused MFMA attention -> avec (1024 blocks, XCD-swizzled, K/V LDS-staged)
  fattn<<<dim3(1024), blk, 0, stream>>>(qwbuf, qrbuf, kbuf, vTbuf, rkbuf, avec);
  // 4. x1 = w + avec @ Wo^T
  mgemm<float><<<dim3(8, 32), blk, 0, stream>>>(avec, wob, nullptr, w,
        x1, nullptr, nullptr, nullptr, nullptr, nullptr, nullptr,
        4096, 1024, 1024, EP_PLAIN, 0);
  // 5. out1 = LN(x1)
  ln_kernel<bf16><<<dim3(4096), blk, 0, stream>>>(x1, ln1g, ln1b, o1);
  // 6. h = relu(out1 @ W1^T + b1)
  mgemm<float><<<dim3(32, 32), blk, 0, stream>>>(o1, w1b, b1, (const float*)nullptr,
        h, nullptr, nullptr, nullptr, nullptr, nullptr, nullptr,
        4096, 4096, 1024, EP_PLAIN, 1);
  // 7. x2 = out1 + h @ W2^T + b2
  mgemm<bf16><<<dim3(8, 32), blk, 0, stream>>>(h, w2b, b2, o1,
        x2, nullptr, nullptr, nullptr, nullptr, nullptr, nullptr,
        4096, 1024, 4096, EP_PLAIN, 0);
  // 8. out = LN(x2) -> fp32
  ln_kernel<float><<<dim3(4096), blk, 0, stream>>>(x2, ln2g, ln2b, (float*)d_out);
}

// Round 4
// 604.131 us; speedup vs baseline: 1.6304x; 1.0376x over previous
//
#include <hip/hip_runtime.h>
#include <hip/hip_bf16.h>

typedef __hip_bfloat16 bf16;

typedef __attribute__((ext_vector_type(8))) short frag8;
typedef __attribute__((ext_vector_type(4))) float f32x4;

__device__ __forceinline__ bf16 f2bf(float f) { return __float2bfloat16(f); }

__device__ __forceinline__ float u16f(unsigned short u) {
  union { unsigned int i; float f; } c; c.i = ((unsigned int)u) << 16; return c.f;
}
__device__ __forceinline__ unsigned short bfbits(float f) {
  union { bf16 b; unsigned short u; } c; c.b = __float2bfloat16(f); return c.u;
}
__device__ __forceinline__ float tof(float x) { return x; }
__device__ __forceinline__ float tof(bf16 x)  { return __bfloat162float(x); }

// async 16B global->LDS copy (m97 pattern)
__device__ __forceinline__ void gload_lds16(const bf16* g, short* l) {
  __builtin_amdgcn_global_load_lds(
      (const __attribute__((address_space(1))) void*)g,
      (__attribute__((address_space(3))) void*)l, 16, 0, 0);
}

#define EP_PLAIN 0
#define EP_QKV   1
#define EP_RK    2

// batched fp32 -> bf16 convert: 8 segments in one launch
struct CvtArgs {
  const float* src[8];
  bf16* dst[8];
  int cum[9];          // cumulative n4 boundaries
};
__global__ __launch_bounds__(256)
void cvt8(CvtArgs a)
{
  const int i = blockIdx.x * 256 + threadIdx.x;
  if (i >= a.cum[8]) return;
  int seg = 7;
  #pragma unroll
  for (int s2 = 6; s2 >= 0; --s2) if (i < a.cum[s2 + 1]) seg = s2;
  const int o = i - a.cum[seg];
  float4 v = ((const float4*)a.src[seg])[o];
  ushort4 u;
  u.x = bfbits(v.x); u.y = bfbits(v.y); u.z = bfbits(v.z); u.w = bfbits(v.w);
  ((ushort4*)a.dst[seg])[o] = u;
}

// MFMA GEMM: C[M,N] = A[M,K] @ W[N,K]^T, bf16 in, fp32 accum.
// 128x128 tile, BK=32, 4 waves (2x2).
// R4: double-buffered stage-ahead K-loop (T3-minimum 2-phase). R3 counters
// showed ~2230 serialized cycles/K-step vs ~300 of work: the old
// sync;stage;sync;compute loop drained vmcnt(0) right after issuing the
// staging loads, exposing full L2/HBM latency every step (FF1 L2-miss 27%).
// Now stage(t+1) is issued BEFORE compute(t): one barrier per step; the
// barrier's implicit vmcnt(0) drain only covers latency not hidden by the
// 16 MFMAs + 8 ds_reads. Reference for this structure: ~620-680 TF.
template<typename TRES>
__global__ __launch_bounds__(256)
void mgemm(const bf16* __restrict__ A, const bf16* __restrict__ W,
           const float* __restrict__ bias, const TRES* __restrict__ res,
           bf16* __restrict__ out,
           bf16* __restrict__ qwb, bf16* __restrict__ qrb,
           bf16* __restrict__ kbo, bf16* __restrict__ vto,
           const float* __restrict__ rwbias, const float* __restrict__ rrbias,
           int M, int N, int K, int mode, int relu)
{
  __shared__ __align__(16) short sA[2][128 * 32];   // 16 KB x2
  __shared__ __align__(16) short sB[2][128 * 32];   // 16 KB x2
  const int tid  = threadIdx.x;
  const int lane = tid & 63;
  const int wave = tid >> 6;
  const int quad = lane >> 4;
  const int l15  = lane & 15;
  const int m0 = blockIdx.y * 128;
  const int n0 = blockIdx.x * 128;
  const int wm = (wave >> 1) * 64;
  const int wn = (wave & 1) * 64;

  const int lr = tid >> 2;
  const int lc = (tid & 3) << 3;

  const bf16* aptr0 = A + (size_t)(m0 + lr) * K + lc;
  const bf16* aptr1 = aptr0 + (size_t)64 * K;
  const bf16* wptr0 = W + (size_t)(n0 + lr) * K + lc;
  const bf16* wptr1 = wptr0 + (size_t)64 * K;

  f32x4 acc[4][4] = {};

  // stage K-slice [kk,kk+32) into buffer buf (linear LDS dest = lane*16B)
  auto stage = [&](int buf, int kk) {
    gload_lds16(aptr0 + kk, &sA[buf][wave * 512]);
    gload_lds16(aptr1 + kk, &sA[buf][2048 + wave * 512]);
    gload_lds16(wptr0 + kk, &sB[buf][wave * 512]);
    gload_lds16(wptr1 + kk, &sB[buf][2048 + wave * 512]);
  };

  stage(0, 0);
  __syncthreads();               // prologue drain: buf0 resident
  int cur = 0;

  for (int kk = 0; kk < K; kk += 32) {
    if (kk + 32 < K) stage(cur ^ 1, kk + 32);   // prefetch next slice
    frag8 af[4], bfr[4];
    #pragma unroll
    for (int t = 0; t < 4; ++t) {
      af[t]  = *(const frag8*)&sA[cur][(wm + t * 16 + l15) * 32 + quad * 8];
      bfr[t] = *(const frag8*)&sB[cur][(wn + t * 16 + l15) * 32 + quad * 8];
    }
    #pragma unroll
    for (int mi = 0; mi < 4; ++mi)
      #pragma unroll
      for (int ni = 0; ni < 4; ++ni)
        acc[mi][ni] = __builtin_amdgcn_mfma_f32_16x16x32_bf16(
            af[mi], bfr[ni], acc[mi][ni], 0, 0, 0);
    __syncthreads();   // drains vmcnt (next slice landed) + lgkm (reads done)
    cur ^= 1;
  }

  #pragma unroll
  for (int mi = 0; mi < 4; ++mi) {
    #pragma unroll
    for (int reg = 0; reg < 4; ++reg) {
      const int row = m0 + wm + mi * 16 + quad * 4 + reg;
      if (mode == EP_PLAIN) {
        bf16* orow = out + (size_t)row * N;
        const TRES* rrow = res ? res + (size_t)row * N : nullptr;
        #pragma unroll
        for (int ni = 0; ni < 4; ++ni) {
          const int col = n0 + wn + ni * 16 + l15;
          float v = acc[mi][ni][reg];
          if (bias) v += bias[col];
          if (relu) v = fmaxf(v, 0.f);
          if (rrow) v += tof(rrow[col]);
          orow[col] = f2bf(v);
        }
      } else if (mode == EP_QKV) {
        const int t = row >> 3, bb = row & 7;
        #pragma unroll
        for (int ni = 0; ni < 4; ++ni) {
          const int col = n0 + wn + ni * 16 + l15;
          const float v = acc[mi][ni][reg];
          const int seg = col >> 10;
          const int cl  = col & 1023;
          const int hn  = cl >> 6, d = cl & 63;
          if (seg == 0) {
            if (t >= 512) {
              const size_t idx = (((size_t)bb * 16 + hn) * 512 + (t - 512)) * 64 + d;
              qwb[idx] = f2bf(v + rwbias[cl]);
              qrb[idx] = f2bf(v + rrbias[cl]);
            }
          } else if (seg == 1) {
            kbo[(((size_t)bb * 16 + hn) * 1024 + t) * 64 + d] = f2bf(v);
          } else {
            vto[(((size_t)bb * 16 + hn) * 64 + d) * 1024 + t] = f2bf(v);
          }
        }
      } else { // EP_RK
        #pragma unroll
        for (int ni = 0; ni < 4; ++ni) {
          const int col = n0 + wn + ni * 16 + l15;
          const int hn = col >> 6, d = col & 63;
          qwb[((size_t)hn * 1024 + row) * 64 + d] = f2bf(acc[mi][ni][reg]);
        }
      }
    }
  }
}

// Fused MFMA attention v6: R0 structure (1024 blocks, 4 waves x 16 rows) +
// LDS staging of K and V tiles shared by all 4 waves (R3: fattn 173 -> ~115us).
__global__ __launch_bounds__(256, 3)
void fattn(const bf16* __restrict__ qw, const bf16* __restrict__ qr,
           const bf16* __restrict__ kb, const bf16* __restrict__ vT,
           const bf16* __restrict__ rk, bf16* __restrict__ avec)
{
  __shared__ __align__(16) short sK[8192];   // 128 j x 64 d bf16, swizzled (16 KB)
  __shared__ __align__(16) short sV[8192];   // 64 d x 128 j bf16, swizzled (16 KB)
  __shared__ __align__(16) unsigned short p_lds[4][16][136]; // 17408 B
  const int tid  = threadIdx.x;
  const int wave = tid >> 6, lane = tid & 63;
  const int quad = lane >> 4, l15 = lane & 15;
  // XCD-locality decode: bid = r + 8*(phi + 16*it), pair = r + 8*phi
  const int bid = blockIdx.x;
  const int r_  = bid & 7;
  const int s_  = bid >> 3;
  const int phi = s_ & 15;
  const int it  = s_ >> 4;            // i-tile 0..7
  const int pr  = r_ + 8 * phi;       // (h,b) pair 0..127
  const int h   = pr & 15;
  const int b   = pr >> 4;
  const int i0  = it * 64;
  const int iw  = i0 + wave * 16;
  const size_t bh = (size_t)b * 16 + h;
  const bf16* kp = kb + bh * 1024 * 64;
  const bf16* vp = vT + bh * 64 * 1024;
  const bf16* rp = rk + (size_t)h * 1024 * 64;

  frag8 aqw[2], aqr[2];
  {
    const bf16* r0 = qw + (bh * 512 + iw + l15) * 64 + quad * 8;
    aqw[0] = *(const frag8*)r0;
    aqw[1] = *(const frag8*)(r0 + 32);
    const bf16* r1 = qr + (bh * 512 + iw + l15) * 64 + quad * 8;
    aqr[0] = *(const frag8*)r1;
    aqr[1] = *(const frag8*)(r1 + 32);
  }

  f32x4 accO[4] = {};
  float m_run[4], l_run[4];
  #pragma unroll
  for (int rg = 0; rg < 4; ++rg) { m_run[rg] = -INFINITY; l_run[rg] = 0.f; }

  // block-uniform step count (i_last = i0+63); low waves' extra tiles are
  // fully masked (s=-inf -> pv=0 -> no contribution)
  const int nsteps = ((i0 + 63 + 512) >> 7) + 1;
  const int offb   = 15 + l15 - quad * 4;

  // stage j-tile [j0s, j0s+128) of K and V into sK/sV.
  // Linear LDS write (gload_lds), inverse-swizzled global source:
  //   content(sK[Lb]) = K[Lb ^ ((row&7)<<4)], row = Lb>>7  (128 B rows)
  //   content(sV[Lb]) = V[Lb ^ ((row&7)<<4)], row = Lb>>8  (256 B rows)
  auto stage = [&](int j0s) {
    #pragma unroll
    for (int c = 0; c < 4; ++c) {
      const int Lb  = c * 4096 + tid * 16;
      short* ldst   = (short*)((char*)sK + (c * 4096 + wave * 1024));
      short* ldstV  = (short*)((char*)sV + (c * 4096 + wave * 1024));
      const int rK  = Lb >> 7;
      const int UK  = Lb ^ ((rK & 7) << 4);
      gload_lds16((const bf16*)((const char*)kp + (size_t)j0s * 128 + UK), ldst);
      const int rV  = Lb >> 8;
      const int UV  = Lb ^ ((rV & 7) << 4);
      const int cbV = UV & 255;      // byte-in-row (row preserved by XOR)
      gload_lds16((const bf16*)((const char*)vp + (size_t)rV * 2048 + (size_t)j0s * 2 + cbV),
                  ldstV);
    }
  };
  stage(0);

  for (int jt = 0; jt < nsteps; ++jt) {
    const int j0 = jt << 7;
    // ---- BD first: global rk loads (L2-resident) overlap K/V staging ----
    const int pbase = 496 + j0 - iw;
    f32x4 bsub[9];
    #pragma unroll
    for (int ns = 0; ns < 9; ++ns) {
      const int prow = min(pbase + ns * 16 + l15, 1023);
      const bf16* rrow = rp + (size_t)prow * 64 + quad * 8;
      frag8 br0 = *(const frag8*)rrow;
      frag8 br1 = *(const frag8*)(rrow + 32);
      f32x4 z = {};
      z = __builtin_amdgcn_mfma_f32_16x16x32_bf16(aqr[0], br0, z, 0,0,0);
      bsub[ns] = __builtin_amdgcn_mfma_f32_16x16x32_bf16(aqr[1], br1, z, 0,0,0);
    }
    __syncthreads();   // sK/sV for this tile are resident
    // ---- AC scores from sK (swizzled ds_read_b128) ----
    f32x4 accS[8] = {};
    #pragma unroll
    for (int ns = 0; ns < 8; ++ns) {
      const int row = ns * 16 + l15;
      const int sw  = (row & 7) << 4;
      frag8 bk0 = *(const frag8*)((const char*)sK + ((row * 128 + quad * 16) ^ sw));
      frag8 bk1 = *(const frag8*)((const char*)sK + ((row * 128 + 64 + quad * 16) ^ sw));
      accS[ns] = __builtin_amdgcn_mfma_f32_16x16x32_bf16(aqw[0], bk0, accS[ns], 0,0,0);
      accS[ns] = __builtin_amdgcn_mfma_f32_16x16x32_bf16(aqw[1], bk1, accS[ns], 0,0,0);
    }
    // ---- in-register shift + combine + mask + tile max ----
    float tmax[4] = {-INFINITY, -INFINITY, -INFINITY, -INFINITY};
    #pragma unroll
    for (int ns = 0; ns < 8; ++ns) {
      #pragma unroll
      for (int rg = 0; rg < 4; ++rg) {
        const int o    = offb - rg;                 // [0,30]
        const int srcl = (quad << 4) | (o & 15);
        const float lo = __shfl(bsub[ns][rg],     srcl, 64);
        const float hi = __shfl(bsub[ns + 1][rg], srcl, 64);
        const float bd = (o & 16) ? hi : lo;
        float s = (accS[ns][rg] + bd) * 0.125f;
        const int j = j0 + ns * 16 + l15;
        s = (j > iw + quad * 4 + rg + 512) ? -INFINITY : s;
        accS[ns][rg] = s;
        tmax[rg] = fmaxf(tmax[rg], s);
      }
    }
    #pragma unroll
    for (int off = 1; off < 16; off <<= 1)
      #pragma unroll
      for (int rg = 0; rg < 4; ++rg)
        tmax[rg] = fmaxf(tmax[rg], __shfl_xor(tmax[rg], off, 64));
    // ---- online softmax update ----
    float alpha[4], tsum[4] = {0.f, 0.f, 0.f, 0.f};
    #pragma unroll
    for (int rg = 0; rg < 4; ++rg) {
      const float nm = fmaxf(m_run[rg], tmax[rg]);
      alpha[rg] = __expf(m_run[rg] - nm);
      m_run[rg] = nm;
    }
    #pragma unroll
    for (int ns = 0; ns < 8; ++ns)
      #pragma unroll
      for (int rg = 0; rg < 4; ++rg) {
        const int rl = quad * 4 + rg;
        const float pv = __expf(accS[ns][rg] - m_run[rg]);
        tsum[rg] += pv;
        p_lds[wave][rl][ns * 16 + l15] = bfbits(pv);
      }
    #pragma unroll
    for (int off = 1; off < 16; off <<= 1)
      #pragma unroll
      for (int rg = 0; rg < 4; ++rg)
        tsum[rg] += __shfl_xor(tsum[rg], off, 64);
    #pragma unroll
    for (int rg = 0; rg < 4; ++rg)
      l_run[rg] = l_run[rg] * alpha[rg] + tsum[rg];
    #pragma unroll
    for (int nd = 0; nd < 4; ++nd)
      #pragma unroll
      for (int rg = 0; rg < 4; ++rg)
        accO[nd][rg] *= alpha[rg];
    __builtin_amdgcn_wave_barrier();
    // ---- PV from sV (swizzled ds_read_b128) ----
    #pragma unroll
    for (int ks = 0; ks < 4; ++ks) {
      frag8 ap = *(const frag8*)&p_lds[wave][l15][ks * 32 + quad * 8];
      #pragma unroll
      for (int nd = 0; nd < 4; ++nd) {
        const int d = nd * 16 + l15;
        frag8 bv = *(const frag8*)((const char*)sV +
                    ((d * 256 + ks * 64 + quad * 16) ^ ((d & 7) << 4)));
        accO[nd] = __builtin_amdgcn_mfma_f32_16x16x32_bf16(ap, bv, accO[nd], 0,0,0);
      }
    }
    __builtin_amdgcn_wave_barrier();
    __syncthreads();   // all waves done reading sK/sV
    if (jt + 1 < nsteps) stage((jt + 1) << 7);
  }

  #pragma unroll
  for (int rg = 0; rg < 4; ++rg) {
    const int i = iw + quad * 4 + rg;
    const float inv = 1.f / l_run[rg];
    #pragma unroll
    for (int nd = 0; nd < 4; ++nd) {
      const int d = nd * 16 + l15;
      avec[((size_t)i * 8 + b) * 1024 + h * 64 + d] = f2bf(accO[nd][rg] * inv);
    }
  }
}

// row LayerNorm over 1024 cols; one block per row.
template<typename TOUT>
__global__ __launch_bounds__(256)
void ln_kernel(const bf16* __restrict__ x, const float* __restrict__ g,
               const float* __restrict__ be, TOUT* __restrict__ out)
{
  __shared__ float red0[4];
  __shared__ float red1[4];
  const int row = blockIdx.x;
  const int tid = threadIdx.x;
  const bf16* xr = x + (size_t)row * 1024;
  ushort4 u = *(const ushort4*)(xr + (tid << 2));
  const float v0 = u16f(u.x), v1 = u16f(u.y), v2 = u16f(u.z), v3 = u16f(u.w);
  float sum = v0 + v1 + v2 + v3;
  #pragma unroll
  for (int off = 1; off < 64; off <<= 1) sum += __shfl_xor(sum, off, 64);
  if ((tid & 63) == 0) red0[tid >> 6] = sum;
  __syncthreads();
  const float mu = (red0[0] + red0[1] + red0[2] + red0[3]) * (1.f / 1024.f);
  const float d0 = v0 - mu, d1 = v1 - mu, d2 = v2 - mu, d3 = v3 - mu;
  float sq = d0*d0 + d1*d1 + d2*d2 + d3*d3;
  #pragma unroll
  for (int off = 1; off < 64; off <<= 1) sq += __shfl_xor(sq, off, 64);
  if ((tid & 63) == 0) red1[tid >> 6] = sq;
  __syncthreads();
  const float var = (red1[0] + red1[1] + red1[2] + red1[3]) * (1.f / 1024.f);
  const float inv = 1.f / sqrtf(var + 1e-5f);
  const int c = tid << 2;
  float4 ug = *(const float4*)(g + c);
  float4 ub = *(const float4*)(be + c);
  TOUT* orow = out + (size_t)row * 1024;
  orow[c+0] = (TOUT)(d0 * inv * ug.x + ub.x);
  orow[c+1] = (TOUT)(d1 * inv * ug.y + ub.y);
  orow[c+2] = (TOUT)(d2 * inv * ug.z + ub.z);
  orow[c+3] = (TOUT)(d3 * inv * ug.w + ub.w);
}

extern "C" void kernel_launch(void* const* d_in, const int* in_sizes, int n_in,
                              void* d_out, int out_size, void* d_ws, size_t ws_size,
                              hipStream_t stream)
{
  const float* w    = (const float*)d_in[0];
  const float* r    = (const float*)d_in[1];
  const float* rwb  = (const float*)d_in[2];
  const float* rrb  = (const float*)d_in[3];
  const float* mems = (const float*)d_in[4];
  // d_in[5] = attn_mask: deterministic (j > i + 512), computed in-kernel
  const float* Wqkv = (const float*)d_in[6];
  const float* Wr   = (const float*)d_in[7];
  const float* Wo   = (const float*)d_in[8];
  const float* ln1g = (const float*)d_in[9];
  const float* ln1b = (const float*)d_in[10];
  const float* W1   = (const float*)d_in[11];
  const float* b1   = (const float*)d_in[12];
  const float* W2   = (const float*)d_in[13];
  const float* b2   = (const float*)d_in[14];
  const float* ln2g = (const float*)d_in[15];
  const float* ln2b = (const float*)d_in[16];

  // Workspace (bf16), liveness-aliased, peak 94 MiB (layout unchanged from R5)
  const size_t MB = 1u << 20;
  char* p = (char*)d_ws;
  bf16* catb  = (bf16*)(p +  0 * MB);
  bf16* wqkvb = (bf16*)(p + 16 * MB);
  bf16* wrb   = (bf16*)(p + 22 * MB);
  bf16* wob   = (bf16*)(p + 24 * MB);
  bf16* w1b   = (bf16*)(p + 26 * MB);
  bf16* w2b   = (bf16*)(p + 34 * MB);
  bf16* qwbuf = (bf16*)(p + 42 * MB);
  bf16* qrbuf = (bf16*)(p + 50 * MB);
  bf16* kbuf  = (bf16*)(p + 58 * MB);
  bf16* vTbuf = (bf16*)(p + 74 * MB);
  bf16* rkbuf = (bf16*)(p + 90 * MB);
  bf16* rb    = (bf16*)(p + 92 * MB);
  bf16* avec  = (bf16*)(p +  0 * MB);
  bf16* x1    = (bf16*)(p +  8 * MB);
  bf16* o1    = (bf16*)(p + 42 * MB);
  bf16* x2    = (bf16*)(p + 50 * MB);
  bf16* h     = (bf16*)(p + 58 * MB);

  dim3 blk(256);
  // 0. fp32 -> bf16 converts (one batched launch)
  {
    CvtArgs a;
    const int n4w = (4096 * 1024) / 4, n4r = (1024 * 1024) / 4,
              n4qkv = (3072 * 1024) / 4;
    a.src[0] = mems; a.dst[0] = catb;                        int n0_ = n4w;
    a.src[1] = w;    a.dst[1] = catb + (size_t)4096 * 1024;  int n1_ = n4w;
    a.src[2] = r;    a.dst[2] = rb;                          int n2_ = n4r;
    a.src[3] = Wqkv; a.dst[3] = wqkvb;                       int n3_ = n4qkv;
    a.src[4] = Wr;   a.dst[4] = wrb;                         int n4_ = n4r;
    a.src[5] = Wo;   a.dst[5] = wob;                         int n5_ = n4r;
    a.src[6] = W1;   a.dst[6] = w1b;                         int n6_ = n4w;
    a.src[7] = W2;   a.dst[7] = w2b;                         int n7_ = n4w;
    const int ns_[8] = {n0_, n1_, n2_, n3_, n4_, n5_, n6_, n7_};
    a.cum[0] = 0;
    for (int s2 = 0; s2 < 8; ++s2) a.cum[s2 + 1] = a.cum[s2] + ns_[s2];
    cvt8<<<dim3((a.cum[8] + 255) / 256), blk, 0, stream>>>(a);
  }

  // 1. heads = cat @ Wqkv^T -> scatter qw/qr (biases added), kb, vT
  mgemm<float><<<dim3(24, 64), blk, 0, stream>>>(catb, wqkvb, nullptr, (const float*)nullptr,
        nullptr, qwbuf, qrbuf, kbuf, vTbuf, rwb, rrb, 8192, 3072, 1024, EP_QKV, 0);
  // 2. rk = r @ Wr^T -> (h,p,d)
  mgemm<float><<<dim3(8, 8), blk, 0, stream>>>(rb, wrb, nullptr, (const float*)nullptr,
        nullptr, rkbuf, nullptr, nullptr, nullptr, nullptr, nullptr,
        1024, 1024, 1024, EP_RK, 0);
  // 3. fused MFMA attention -> avec (1024 blocks, XCD-swizzled, K/V LDS-staged)
  fattn<<<dim3(1024), blk, 0, stream>>>(qwbuf, qrbuf, kbuf, vTbuf, rkbuf, avec);
  // 4. x1 = w + avec @ Wo^T
  mgemm<float><<<dim3(8, 32), blk, 0, stream>>>(avec, wob, nullptr, w,
        x1, nullptr, nullptr, nullptr, nullptr, nullptr, nullptr,
        4096, 1024, 1024, EP_PLAIN, 0);
  // 5. out1 = LN(x1)
  ln_kernel<bf16><<<dim3(4096), blk, 0, stream>>>(x1, ln1g, ln1b, o1);
  // 6. h = relu(out1 @ W1^T + b1)
  mgemm<float><<<dim3(32, 32), blk, 0, stream>>>(o1, w1b, b1, (const float*)nullptr,
        h, nullptr, nullptr, nullptr, nullptr, nullptr, nullptr,
        4096, 4096, 1024, EP_PLAIN, 1);
  // 7. x2 = out1 + h @ W2^T + b2
  mgemm<bf16><<<dim3(8, 32), blk, 0, stream>>>(h, w2b, b2, o1,
        x2, nullptr, nullptr, nullptr, nullptr, nullptr, nullptr,
        4096, 1024, 4096, EP_PLAIN, 0);
  // 8. out = LN(x2) -> fp32
  ln_kernel<float><<<dim3(4096), blk, 0, stream>>>(x2, ln2g, ln2b, (float*)d_out);
}

// Round 5
// 556.083 us; speedup vs baseline: 1.7713x; 1.0864x over previous
//
#include <hip/hip_runtime.h>
#include <hip/hip_bf16.h>

typedef __hip_bfloat16 bf16;

typedef __attribute__((ext_vector_type(8))) short frag8;
typedef __attribute__((ext_vector_type(4))) float f32x4;

__device__ __forceinline__ bf16 f2bf(float f) { return __float2bfloat16(f); }

__device__ __forceinline__ float u16f(unsigned short u) {
  union { unsigned int i; float f; } c; c.i = ((unsigned int)u) << 16; return c.f;
}
__device__ __forceinline__ unsigned short bfbits(float f) {
  union { bf16 b; unsigned short u; } c; c.b = __float2bfloat16(f); return c.u;
}
__device__ __forceinline__ float tof(float x) { return x; }
__device__ __forceinline__ float tof(bf16 x)  { return __bfloat162float(x); }

// async 16B global->LDS copy (m97 pattern)
__device__ __forceinline__ void gload_lds16(const bf16* g, short* l) {
  __builtin_amdgcn_global_load_lds(
      (const __attribute__((address_space(1))) void*)g,
      (__attribute__((address_space(3))) void*)l, 16, 0, 0);
}

#define EP_PLAIN 0
#define EP_RK    2
#define EP_Q     3
#define EP_KV    4

// batched fp32 -> bf16 convert: 8 segments in one launch
struct CvtArgs {
  const float* src[8];
  bf16* dst[8];
  int cum[9];          // cumulative n4 boundaries
};
__global__ __launch_bounds__(256)
void cvt8(CvtArgs a)
{
  const int i = blockIdx.x * 256 + threadIdx.x;
  if (i >= a.cum[8]) return;
  int seg = 7;
  #pragma unroll
  for (int s2 = 6; s2 >= 0; --s2) if (i < a.cum[s2 + 1]) seg = s2;
  const int o = i - a.cum[seg];
  float4 v = ((const float4*)a.src[seg])[o];
  ushort4 u;
  u.x = bfbits(v.x); u.y = bfbits(v.y); u.z = bfbits(v.z); u.w = bfbits(v.w);
  ((ushort4*)a.dst[seg])[o] = u;
}

// MFMA GEMM: C[M,N] = A[M,K] @ W[N,K]^T, bf16 in, fp32 accum.
// 128x128 tile, BK=32, 4 waves (2x2), double-buffered stage-ahead (R4).
// R5: QKV split into EP_KV (M=8192,N=2048) + EP_Q (M=4096 = t>=512 rows only,
// N=1024): removes the 8.6 GF of discarded q compute. EP_KV's V half
// (block-uniform n0>=1024) stages its output tile through the retired 32 KB
// staging smem in a [tl][rowid ^ (tl<<1)] layout (XOR keeps both the 2B
// write phase and the 16-tl read-back conflict-free), then emits two
// coalesced 16B stores per vT row. R4 counters showed the old direct vT
// scatter cost: 64 distinct lines per wave-store, WRITE 85 MB vs 50 payload.
template<typename TRES>
__global__ __launch_bounds__(256)
void mgemm(const bf16* __restrict__ A, const bf16* __restrict__ W,
           const float* __restrict__ bias, const TRES* __restrict__ res,
           bf16* __restrict__ out,
           bf16* __restrict__ qwb, bf16* __restrict__ qrb,
           bf16* __restrict__ kbo, bf16* __restrict__ vto,
           const float* __restrict__ rwbias, const float* __restrict__ rrbias,
           int M, int N, int K, int mode, int relu)
{
  __shared__ __align__(16) short smem[16384];   // 32 KB: 2x sA + 2x sB / vT stage
  short (*sA)[4096] = reinterpret_cast<short(*)[4096]>(smem);
  short (*sB)[4096] = reinterpret_cast<short(*)[4096]>(smem + 8192);
  const int tid  = threadIdx.x;
  const int lane = tid & 63;
  const int wave = tid >> 6;
  const int quad = lane >> 4;
  const int l15  = lane & 15;
  const int m0 = blockIdx.y * 128;
  const int n0 = blockIdx.x * 128;
  const int wm = (wave >> 1) * 64;
  const int wn = (wave & 1) * 64;

  const int lr = tid >> 2;
  const int lc = (tid & 3) << 3;

  const bf16* aptr0 = A + (size_t)(m0 + lr) * K + lc;
  const bf16* aptr1 = aptr0 + (size_t)64 * K;
  const bf16* wptr0 = W + (size_t)(n0 + lr) * K + lc;
  const bf16* wptr1 = wptr0 + (size_t)64 * K;

  f32x4 acc[4][4] = {};

  // stage K-slice [kk,kk+32) into buffer buf (linear LDS dest = lane*16B)
  auto stage = [&](int buf, int kk) {
    gload_lds16(aptr0 + kk, &sA[buf][wave * 512]);
    gload_lds16(aptr1 + kk, &sA[buf][2048 + wave * 512]);
    gload_lds16(wptr0 + kk, &sB[buf][wave * 512]);
    gload_lds16(wptr1 + kk, &sB[buf][2048 + wave * 512]);
  };

  stage(0, 0);
  __syncthreads();               // prologue drain: buf0 resident
  int cur = 0;

  for (int kk = 0; kk < K; kk += 32) {
    if (kk + 32 < K) stage(cur ^ 1, kk + 32);   // prefetch next slice
    frag8 af[4], bfr[4];
    #pragma unroll
    for (int t = 0; t < 4; ++t) {
      af[t]  = *(const frag8*)&sA[cur][(wm + t * 16 + l15) * 32 + quad * 8];
      bfr[t] = *(const frag8*)&sB[cur][(wn + t * 16 + l15) * 32 + quad * 8];
    }
    #pragma unroll
    for (int mi = 0; mi < 4; ++mi)
      #pragma unroll
      for (int ni = 0; ni < 4; ++ni)
        acc[mi][ni] = __builtin_amdgcn_mfma_f32_16x16x32_bf16(
            af[mi], bfr[ni], acc[mi][ni], 0, 0, 0);
    __syncthreads();   // drains vmcnt (next slice landed) + lgkm (reads done)
    cur ^= 1;
  }
  // all waves are past their LDS reads here: smem is reusable.

  if (mode == EP_KV && n0 >= 1024) {
    // ---- V half: LDS-transposed coalesced epilogue ----
    // write phase: smem[tl*1024 + (rowid ^ (tl<<1))], rowid=(bbl*2+hn2)*64+d
    #pragma unroll
    for (int mi = 0; mi < 4; ++mi) {
      #pragma unroll
      for (int reg = 0; reg < 4; ++reg) {
        const int rowl = wm + mi * 16 + quad * 4 + reg;
        const int bbl  = rowl & 7;
        const int tl   = rowl >> 3;
        #pragma unroll
        for (int ni = 0; ni < 4; ++ni) {
          const int coll = wn + ni * 16 + l15;          // 0..127
          const int hn2  = coll >> 6;
          const int d    = coll & 63;
          const int rowid = (bbl * 2 + hn2) * 64 + d;
          smem[tl * 1024 + (rowid ^ (tl << 1))] =
              (short)bfbits(acc[mi][ni][reg]);
        }
      }
    }
    __syncthreads();
    // read phase: each thread emits 4 vT rows (16 t each) as 2x16B stores
    const int hnb = (n0 >> 6) - 16;        // head base for this block
    const int t0  = m0 >> 3;
    #pragma unroll
    for (int p = 0; p < 4; ++p) {
      const int r   = p * 256 + tid;       // rowid 0..1023
      const int bbl = r >> 7;
      const int hn2 = (r >> 6) & 1;
      const int d   = r & 63;
      unsigned short tmp[16];
      #pragma unroll
      for (int tl = 0; tl < 16; ++tl)
        tmp[tl] = (unsigned short)smem[tl * 1024 + (r ^ (tl << 1))];
      bf16* dst = vto + ((size_t)(bbl * 16 + hnb + hn2) * 64 + d) * 1024 + t0;
      *(frag8*)dst       = *(const frag8*)&tmp[0];
      *(frag8*)(dst + 8) = *(const frag8*)&tmp[8];
    }
    return;
  }

  #pragma unroll
  for (int mi = 0; mi < 4; ++mi) {
    #pragma unroll
    for (int reg = 0; reg < 4; ++reg) {
      const int rowl = wm + mi * 16 + quad * 4 + reg;
      const int row  = m0 + rowl;
      if (mode == EP_PLAIN) {
        bf16* orow = out + (size_t)row * N;
        const TRES* rrow = res ? res + (size_t)row * N : nullptr;
        #pragma unroll
        for (int ni = 0; ni < 4; ++ni) {
          const int col = n0 + wn + ni * 16 + l15;
          float v = acc[mi][ni][reg];
          if (bias) v += bias[col];
          if (relu) v = fmaxf(v, 0.f);
          if (rrow) v += tof(rrow[col]);
          orow[col] = f2bf(v);
        }
      } else if (mode == EP_KV) {
        // K half (n0 < 1024): direct stores, 32B/quad chunks
        const int t = row >> 3, bb = row & 7;
        #pragma unroll
        for (int ni = 0; ni < 4; ++ni) {
          const int col = n0 + wn + ni * 16 + l15;
          const int hn = col >> 6, d = col & 63;
          kbo[((size_t)(bb * 16 + hn) * 1024 + t) * 64 + d] =
              f2bf(acc[mi][ni][reg]);
        }
      } else if (mode == EP_Q) {
        // rows are cat rows 4096.. -> t = 512 + row>>3, tq = row>>3
        const int tq = row >> 3, bb = row & 7;
        #pragma unroll
        for (int ni = 0; ni < 4; ++ni) {
          const int col = n0 + wn + ni * 16 + l15;  // 0..1023
          const int hn = col >> 6, d = col & 63;
          const float v = acc[mi][ni][reg];
          const size_t idx = ((size_t)(bb * 16 + hn) * 512 + tq) * 64 + d;
          qwb[idx] = f2bf(v + rwbias[col]);
          qrb[idx] = f2bf(v + rrbias[col]);
        }
      } else { // EP_RK
        #pragma unroll
        for (int ni = 0; ni < 4; ++ni) {
          const int col = n0 + wn + ni * 16 + l15;
          const int hn = col >> 6, d = col & 63;
          qwb[((size_t)hn * 1024 + row) * 64 + d] = f2bf(acc[mi][ni][reg]);
        }
      }
    }
  }
}

// Fused MFMA attention v6: R0 structure (1024 blocks, 4 waves x 16 rows) +
// LDS staging of K and V tiles shared by all 4 waves (R3: fattn 173 -> ~115us).
__global__ __launch_bounds__(256, 3)
void fattn(const bf16* __restrict__ qw, const bf16* __restrict__ qr,
           const bf16* __restrict__ kb, const bf16* __restrict__ vT,
           const bf16* __restrict__ rk, bf16* __restrict__ avec)
{
  __shared__ __align__(16) short sK[8192];   // 128 j x 64 d bf16, swizzled (16 KB)
  __shared__ __align__(16) short sV[8192];   // 64 d x 128 j bf16, swizzled (16 KB)
  __shared__ __align__(16) unsigned short p_lds[4][16][136]; // 17408 B
  const int tid  = threadIdx.x;
  const int wave = tid >> 6, lane = tid & 63;
  const int quad = lane >> 4, l15 = lane & 15;
  // XCD-locality decode: bid = r + 8*(phi + 16*it), pair = r + 8*phi
  const int bid = blockIdx.x;
  const int r_  = bid & 7;
  const int s_  = bid >> 3;
  const int phi = s_ & 15;
  const int it  = s_ >> 4;            // i-tile 0..7
  const int pr  = r_ + 8 * phi;       // (h,b) pair 0..127
  const int h   = pr & 15;
  const int b   = pr >> 4;
  const int i0  = it * 64;
  const int iw  = i0 + wave * 16;
  const size_t bh = (size_t)b * 16 + h;
  const bf16* kp = kb + bh * 1024 * 64;
  const bf16* vp = vT + bh * 64 * 1024;
  const bf16* rp = rk + (size_t)h * 1024 * 64;

  frag8 aqw[2], aqr[2];
  {
    const bf16* r0 = qw + (bh * 512 + iw + l15) * 64 + quad * 8;
    aqw[0] = *(const frag8*)r0;
    aqw[1] = *(const frag8*)(r0 + 32);
    const bf16* r1 = qr + (bh * 512 + iw + l15) * 64 + quad * 8;
    aqr[0] = *(const frag8*)r1;
    aqr[1] = *(const frag8*)(r1 + 32);
  }

  f32x4 accO[4] = {};
  float m_run[4], l_run[4];
  #pragma unroll
  for (int rg = 0; rg < 4; ++rg) { m_run[rg] = -INFINITY; l_run[rg] = 0.f; }

  // block-uniform step count (i_last = i0+63); low waves' extra tiles are
  // fully masked (s=-inf -> pv=0 -> no contribution)
  const int nsteps = ((i0 + 63 + 512) >> 7) + 1;
  const int offb   = 15 + l15 - quad * 4;

  // stage j-tile [j0s, j0s+128) of K and V into sK/sV.
  // Linear LDS write (gload_lds), inverse-swizzled global source:
  //   content(sK[Lb]) = K[Lb ^ ((row&7)<<4)], row = Lb>>7  (128 B rows)
  //   content(sV[Lb]) = V[Lb ^ ((row&7)<<4)], row = Lb>>8  (256 B rows)
  auto stage = [&](int j0s) {
    #pragma unroll
    for (int c = 0; c < 4; ++c) {
      const int Lb  = c * 4096 + tid * 16;
      short* ldst   = (short*)((char*)sK + (c * 4096 + wave * 1024));
      short* ldstV  = (short*)((char*)sV + (c * 4096 + wave * 1024));
      const int rK  = Lb >> 7;
      const int UK  = Lb ^ ((rK & 7) << 4);
      gload_lds16((const bf16*)((const char*)kp + (size_t)j0s * 128 + UK), ldst);
      const int rV  = Lb >> 8;
      const int UV  = Lb ^ ((rV & 7) << 4);
      const int cbV = UV & 255;      // byte-in-row (row preserved by XOR)
      gload_lds16((const bf16*)((const char*)vp + (size_t)rV * 2048 + (size_t)j0s * 2 + cbV),
                  ldstV);
    }
  };
  stage(0);

  for (int jt = 0; jt < nsteps; ++jt) {
    const int j0 = jt << 7;
    // ---- BD first: global rk loads (L2-resident) overlap K/V staging ----
    const int pbase = 496 + j0 - iw;
    f32x4 bsub[9];
    #pragma unroll
    for (int ns = 0; ns < 9; ++ns) {
      const int prow = min(pbase + ns * 16 + l15, 1023);
      const bf16* rrow = rp + (size_t)prow * 64 + quad * 8;
      frag8 br0 = *(const frag8*)rrow;
      frag8 br1 = *(const frag8*)(rrow + 32);
      f32x4 z = {};
      z = __builtin_amdgcn_mfma_f32_16x16x32_bf16(aqr[0], br0, z, 0,0,0);
      bsub[ns] = __builtin_amdgcn_mfma_f32_16x16x32_bf16(aqr[1], br1, z, 0,0,0);
    }
    __syncthreads();   // sK/sV for this tile are resident
    // ---- AC scores from sK (swizzled ds_read_b128) ----
    f32x4 accS[8] = {};
    #pragma unroll
    for (int ns = 0; ns < 8; ++ns) {
      const int row = ns * 16 + l15;
      const int sw  = (row & 7) << 4;
      frag8 bk0 = *(const frag8*)((const char*)sK + ((row * 128 + quad * 16) ^ sw));
      frag8 bk1 = *(const frag8*)((const char*)sK + ((row * 128 + 64 + quad * 16) ^ sw));
      accS[ns] = __builtin_amdgcn_mfma_f32_16x16x32_bf16(aqw[0], bk0, accS[ns], 0,0,0);
      accS[ns] = __builtin_amdgcn_mfma_f32_16x16x32_bf16(aqw[1], bk1, accS[ns], 0,0,0);
    }
    // ---- in-register shift + combine + mask + tile max ----
    float tmax[4] = {-INFINITY, -INFINITY, -INFINITY, -INFINITY};
    #pragma unroll
    for (int ns = 0; ns < 8; ++ns) {
      #pragma unroll
      for (int rg = 0; rg < 4; ++rg) {
        const int o    = offb - rg;                 // [0,30]
        const int srcl = (quad << 4) | (o & 15);
        const float lo = __shfl(bsub[ns][rg],     srcl, 64);
        const float hi = __shfl(bsub[ns + 1][rg], srcl, 64);
        const float bd = (o & 16) ? hi : lo;
        float s = (accS[ns][rg] + bd) * 0.125f;
        const int j = j0 + ns * 16 + l15;
        s = (j > iw + quad * 4 + rg + 512) ? -INFINITY : s;
        accS[ns][rg] = s;
        tmax[rg] = fmaxf(tmax[rg], s);
      }
    }
    #pragma unroll
    for (int off = 1; off < 16; off <<= 1)
      #pragma unroll
      for (int rg = 0; rg < 4; ++rg)
        tmax[rg] = fmaxf(tmax[rg], __shfl_xor(tmax[rg], off, 64));
    // ---- online softmax update ----
    float alpha[4], tsum[4] = {0.f, 0.f, 0.f, 0.f};
    #pragma unroll
    for (int rg = 0; rg < 4; ++rg) {
      const float nm = fmaxf(m_run[rg], tmax[rg]);
      alpha[rg] = __expf(m_run[rg] - nm);
      m_run[rg] = nm;
    }
    #pragma unroll
    for (int ns = 0; ns < 8; ++ns)
      #pragma unroll
      for (int rg = 0; rg < 4; ++rg) {
        const int rl = quad * 4 + rg;
        const float pv = __expf(accS[ns][rg] - m_run[rg]);
        tsum[rg] += pv;
        p_lds[wave][rl][ns * 16 + l15] = bfbits(pv);
      }
    #pragma unroll
    for (int off = 1; off < 16; off <<= 1)
      #pragma unroll
      for (int rg = 0; rg < 4; ++rg)
        tsum[rg] += __shfl_xor(tsum[rg], off, 64);
    #pragma unroll
    for (int rg = 0; rg < 4; ++rg)
      l_run[rg] = l_run[rg] * alpha[rg] + tsum[rg];
    #pragma unroll
    for (int nd = 0; nd < 4; ++nd)
      #pragma unroll
      for (int rg = 0; rg < 4; ++rg)
        accO[nd][rg] *= alpha[rg];
    __builtin_amdgcn_wave_barrier();
    // ---- PV from sV (swizzled ds_read_b128) ----
    #pragma unroll
    for (int ks = 0; ks < 4; ++ks) {
      frag8 ap = *(const frag8*)&p_lds[wave][l15][ks * 32 + quad * 8];
      #pragma unroll
      for (int nd = 0; nd < 4; ++nd) {
        const int d = nd * 16 + l15;
        frag8 bv = *(const frag8*)((const char*)sV +
                    ((d * 256 + ks * 64 + quad * 16) ^ ((d & 7) << 4)));
        accO[nd] = __builtin_amdgcn_mfma_f32_16x16x32_bf16(ap, bv, accO[nd], 0,0,0);
      }
    }
    __builtin_amdgcn_wave_barrier();
    __syncthreads();   // all waves done reading sK/sV
    if (jt + 1 < nsteps) stage((jt + 1) << 7);
  }

  #pragma unroll
  for (int rg = 0; rg < 4; ++rg) {
    const int i = iw + quad * 4 + rg;
    const float inv = 1.f / l_run[rg];
    #pragma unroll
    for (int nd = 0; nd < 4; ++nd) {
      const int d = nd * 16 + l15;
      avec[((size_t)i * 8 + b) * 1024 + h * 64 + d] = f2bf(accO[nd][rg] * inv);
    }
  }
}

// row LayerNorm over 1024 cols; one block per row.
template<typename TOUT>
__global__ __launch_bounds__(256)
void ln_kernel(const bf16* __restrict__ x, const float* __restrict__ g,
               const float* __restrict__ be, TOUT* __restrict__ out)
{
  __shared__ float red0[4];
  __shared__ float red1[4];
  const int row = blockIdx.x;
  const int tid = threadIdx.x;
  const bf16* xr = x + (size_t)row * 1024;
  ushort4 u = *(const ushort4*)(xr + (tid << 2));
  const float v0 = u16f(u.x), v1 = u16f(u.y), v2 = u16f(u.z), v3 = u16f(u.w);
  float sum = v0 + v1 + v2 + v3;
  #pragma unroll
  for (int off = 1; off < 64; off <<= 1) sum += __shfl_xor(sum, off, 64);
  if ((tid & 63) == 0) red0[tid >> 6] = sum;
  __syncthreads();
  const float mu = (red0[0] + red0[1] + red0[2] + red0[3]) * (1.f / 1024.f);
  const float d0 = v0 - mu, d1 = v1 - mu, d2 = v2 - mu, d3 = v3 - mu;
  float sq = d0*d0 + d1*d1 + d2*d2 + d3*d3;
  #pragma unroll
  for (int off = 1; off < 64; off <<= 1) sq += __shfl_xor(sq, off, 64);
  if ((tid & 63) == 0) red1[tid >> 6] = sq;
  __syncthreads();
  const float var = (red1[0] + red1[1] + red1[2] + red1[3]) * (1.f / 1024.f);
  const float inv = 1.f / sqrtf(var + 1e-5f);
  const int c = tid << 2;
  float4 ug = *(const float4*)(g + c);
  float4 ub = *(const float4*)(be + c);
  TOUT* orow = out + (size_t)row * 1024;
  orow[c+0] = (TOUT)(d0 * inv * ug.x + ub.x);
  orow[c+1] = (TOUT)(d1 * inv * ug.y + ub.y);
  orow[c+2] = (TOUT)(d2 * inv * ug.z + ub.z);
  orow[c+3] = (TOUT)(d3 * inv * ug.w + ub.w);
}

extern "C" void kernel_launch(void* const* d_in, const int* in_sizes, int n_in,
                              void* d_out, int out_size, void* d_ws, size_t ws_size,
                              hipStream_t stream)
{
  const float* w    = (const float*)d_in[0];
  const float* r    = (const float*)d_in[1];
  const float* rwb  = (const float*)d_in[2];
  const float* rrb  = (const float*)d_in[3];
  const float* mems = (const float*)d_in[4];
  // d_in[5] = attn_mask: deterministic (j > i + 512), computed in-kernel
  const float* Wqkv = (const float*)d_in[6];
  const float* Wr   = (const float*)d_in[7];
  const float* Wo   = (const float*)d_in[8];
  const float* ln1g = (const float*)d_in[9];
  const float* ln1b = (const float*)d_in[10];
  const float* W1   = (const float*)d_in[11];
  const float* b1   = (const float*)d_in[12];
  const float* W2   = (const float*)d_in[13];
  const float* b2   = (const float*)d_in[14];
  const float* ln2g = (const float*)d_in[15];
  const float* ln2b = (const float*)d_in[16];

  // Workspace (bf16), liveness-aliased, peak 94 MiB (layout unchanged from R5)
  const size_t MB = 1u << 20;
  char* p = (char*)d_ws;
  bf16* catb  = (bf16*)(p +  0 * MB);
  bf16* wqkvb = (bf16*)(p + 16 * MB);
  bf16* wrb   = (bf16*)(p + 22 * MB);
  bf16* wob   = (bf16*)(p + 24 * MB);
  bf16* w1b   = (bf16*)(p + 26 * MB);
  bf16* w2b   = (bf16*)(p + 34 * MB);
  bf16* qwbuf = (bf16*)(p + 42 * MB);
  bf16* qrbuf = (bf16*)(p + 50 * MB);
  bf16* kbuf  = (bf16*)(p + 58 * MB);
  bf16* vTbuf = (bf16*)(p + 74 * MB);
  bf16* rkbuf = (bf16*)(p + 90 * MB);
  bf16* rb    = (bf16*)(p + 92 * MB);
  bf16* avec  = (bf16*)(p +  0 * MB);
  bf16* x1    = (bf16*)(p +  8 * MB);
  bf16* o1    = (bf16*)(p + 42 * MB);
  bf16* x2    = (bf16*)(p + 50 * MB);
  bf16* h     = (bf16*)(p + 58 * MB);

  dim3 blk(256);
  // 0. fp32 -> bf16 converts (one batched launch)
  {
    CvtArgs a;
    const int n4w = (4096 * 1024) / 4, n4r = (1024 * 1024) / 4,
              n4qkv = (3072 * 1024) / 4;
    a.src[0] = mems; a.dst[0] = catb;                        int n0_ = n4w;
    a.src[1] = w;    a.dst[1] = catb + (size_t)4096 * 1024;  int n1_ = n4w;
    a.src[2] = r;    a.dst[2] = rb;                          int n2_ = n4r;
    a.src[3] = Wqkv; a.dst[3] = wqkvb;                       int n3_ = n4qkv;
    a.src[4] = Wr;   a.dst[4] = wrb;                         int n4_ = n4r;
    a.src[5] = Wo;   a.dst[5] = wob;                         int n5_ = n4r;
    a.src[6] = W1;   a.dst[6] = w1b;                         int n6_ = n4w;
    a.src[7] = W2;   a.dst[7] = w2b;                         int n7_ = n4w;
    const int ns_[8] = {n0_, n1_, n2_, n3_, n4_, n5_, n6_, n7_};
    a.cum[0] = 0;
    for (int s2 = 0; s2 < 8; ++s2) a.cum[s2 + 1] = a.cum[s2] + ns_[s2];
    cvt8<<<dim3((a.cum[8] + 255) / 256), blk, 0, stream>>>(a);
  }

  // 1a. K/V projection: cat @ Wqkv[1024:3072]^T -> kb (direct) + vT (LDS-coalesced)
  mgemm<float><<<dim3(16, 64), blk, 0, stream>>>(catb, wqkvb + (size_t)1024 * 1024,
        nullptr, (const float*)nullptr, nullptr, nullptr, nullptr, kbuf, vTbuf,
        nullptr, nullptr, 8192, 2048, 1024, EP_KV, 0);
  // 1b. Q projection: only rows t>=512 (cat rows 4096..8191), biases fused
  mgemm<float><<<dim3(8, 32), blk, 0, stream>>>(catb + (size_t)4096 * 1024, wqkvb,
        nullptr, (const float*)nullptr, nullptr, qwbuf, qrbuf, nullptr, nullptr,
        rwb, rrb, 4096, 1024, 1024, EP_Q, 0);
  // 2. rk = r @ Wr^T -> (h,p,d)
  mgemm<float><<<dim3(8, 8), blk, 0, stream>>>(rb, wrb, nullptr, (const float*)nullptr,
        nullptr, rkbuf, nullptr, nullptr, nullptr, nullptr, nullptr,
        1024, 1024, 1024, EP_RK, 0);
  // 3. fused MFMA attention -> avec (1024 blocks, XCD-swizzled, K/V LDS-staged)
  fattn<<<dim3(1024), blk, 0, stream>>>(qwbuf, qrbuf, kbuf, vTbuf, rkbuf, avec);
  // 4. x1 = w + avec @ Wo^T
  mgemm<float><<<dim3(8, 32), blk, 0, stream>>>(avec, wob, nullptr, w,
        x1, nullptr, nullptr, nullptr, nullptr, nullptr, nullptr,
        4096, 1024, 1024, EP_PLAIN, 0);
  // 5. out1 = LN(x1)
  ln_kernel<bf16><<<dim3(4096), blk, 0, stream>>>(x1, ln1g, ln1b, o1);
  // 6. h = relu(out1 @ W1^T + b1)
  mgemm<float><<<dim3(32, 32), blk, 0, stream>>>(o1, w1b, b1, (const float*)nullptr,
        h, nullptr, nullptr, nullptr, nullptr, nullptr, nullptr,
        4096, 4096, 1024, EP_PLAIN, 1);
  // 7. x2 = out1 + h @ W2^T + b2
  mgemm<bf16><<<dim3(8, 32), blk, 0, stream>>>(h, w2b, b2, o1,
        x2, nullptr, nullptr, nullptr, nullptr, nullptr, nullptr,
        4096, 1024, 4096, EP_PLAIN, 0);
  // 8. out = LN(x2) -> fp32
  ln_kernel<float><<<dim3(4096), blk, 0, stream>>>(x2, ln2g, ln2b, (float*)d_out);
}

// Round 6
// 542.167 us; speedup vs baseline: 1.8167x; 1.0257x over previous
//
#include <hip/hip_runtime.h>
#include <hip/hip_bf16.h>

typedef __hip_bfloat16 bf16;

typedef __attribute__((ext_vector_type(8))) short frag8;
typedef __attribute__((ext_vector_type(4))) float f32x4;

__device__ __forceinline__ bf16 f2bf(float f) { return __float2bfloat16(f); }

__device__ __forceinline__ float u16f(unsigned short u) {
  union { unsigned int i; float f; } c; c.i = ((unsigned int)u) << 16; return c.f;
}
__device__ __forceinline__ unsigned short bfbits(float f) {
  union { bf16 b; unsigned short u; } c; c.b = __float2bfloat16(f); return c.u;
}
__device__ __forceinline__ float tof(float x) { return x; }
__device__ __forceinline__ float tof(bf16 x)  { return __bfloat162float(x); }

// async 16B global->LDS copy (m97 pattern)
__device__ __forceinline__ void gload_lds16(const bf16* g, short* l) {
  __builtin_amdgcn_global_load_lds(
      (const __attribute__((address_space(1))) void*)g,
      (__attribute__((address_space(3))) void*)l, 16, 0, 0);
}

#define EP_PLAIN 0
#define EP_RK    2
#define EP_Q     3
#define EP_KV    4

// batched fp32 -> bf16 convert: 8 segments in one launch
struct CvtArgs {
  const float* src[8];
  bf16* dst[8];
  int cum[9];          // cumulative n4 boundaries
};
__global__ __launch_bounds__(256)
void cvt8(CvtArgs a)
{
  const int i = blockIdx.x * 256 + threadIdx.x;
  if (i >= a.cum[8]) return;
  int seg = 7;
  #pragma unroll
  for (int s2 = 6; s2 >= 0; --s2) if (i < a.cum[s2 + 1]) seg = s2;
  const int o = i - a.cum[seg];
  float4 v = ((const float4*)a.src[seg])[o];
  ushort4 u;
  u.x = bfbits(v.x); u.y = bfbits(v.y); u.z = bfbits(v.z); u.w = bfbits(v.w);
  ((ushort4*)a.dst[seg])[o] = u;
}

// MFMA GEMM: C[M,N] = A[M,K] @ W[N,K]^T, bf16 in, fp32 accum.
// 128x128 tile, BK=32, 4 waves (2x2), double-buffered stage-ahead (R4).
// R5: QKV split into EP_KV + EP_Q; EP_KV's V half uses an LDS-transposed
// coalesced epilogue (WRITE amplification 85->~50 MB).
template<typename TRES>
__global__ __launch_bounds__(256)
void mgemm(const bf16* __restrict__ A, const bf16* __restrict__ W,
           const float* __restrict__ bias, const TRES* __restrict__ res,
           bf16* __restrict__ out,
           bf16* __restrict__ qwb, bf16* __restrict__ qrb,
           bf16* __restrict__ kbo, bf16* __restrict__ vto,
           const float* __restrict__ rwbias, const float* __restrict__ rrbias,
           int M, int N, int K, int mode, int relu)
{
  __shared__ __align__(16) short smem[16384];   // 32 KB: 2x sA + 2x sB / vT stage
  short (*sA)[4096] = reinterpret_cast<short(*)[4096]>(smem);
  short (*sB)[4096] = reinterpret_cast<short(*)[4096]>(smem + 8192);
  const int tid  = threadIdx.x;
  const int lane = tid & 63;
  const int wave = tid >> 6;
  const int quad = lane >> 4;
  const int l15  = lane & 15;
  const int m0 = blockIdx.y * 128;
  const int n0 = blockIdx.x * 128;
  const int wm = (wave >> 1) * 64;
  const int wn = (wave & 1) * 64;

  const int lr = tid >> 2;
  const int lc = (tid & 3) << 3;

  const bf16* aptr0 = A + (size_t)(m0 + lr) * K + lc;
  const bf16* aptr1 = aptr0 + (size_t)64 * K;
  const bf16* wptr0 = W + (size_t)(n0 + lr) * K + lc;
  const bf16* wptr1 = wptr0 + (size_t)64 * K;

  f32x4 acc[4][4] = {};

  // stage K-slice [kk,kk+32) into buffer buf (linear LDS dest = lane*16B)
  auto stage = [&](int buf, int kk) {
    gload_lds16(aptr0 + kk, &sA[buf][wave * 512]);
    gload_lds16(aptr1 + kk, &sA[buf][2048 + wave * 512]);
    gload_lds16(wptr0 + kk, &sB[buf][wave * 512]);
    gload_lds16(wptr1 + kk, &sB[buf][2048 + wave * 512]);
  };

  stage(0, 0);
  __syncthreads();               // prologue drain: buf0 resident
  int cur = 0;

  for (int kk = 0; kk < K; kk += 32) {
    if (kk + 32 < K) stage(cur ^ 1, kk + 32);   // prefetch next slice
    frag8 af[4], bfr[4];
    #pragma unroll
    for (int t = 0; t < 4; ++t) {
      af[t]  = *(const frag8*)&sA[cur][(wm + t * 16 + l15) * 32 + quad * 8];
      bfr[t] = *(const frag8*)&sB[cur][(wn + t * 16 + l15) * 32 + quad * 8];
    }
    #pragma unroll
    for (int mi = 0; mi < 4; ++mi)
      #pragma unroll
      for (int ni = 0; ni < 4; ++ni)
        acc[mi][ni] = __builtin_amdgcn_mfma_f32_16x16x32_bf16(
            af[mi], bfr[ni], acc[mi][ni], 0, 0, 0);
    __syncthreads();   // drains vmcnt (next slice landed) + lgkm (reads done)
    cur ^= 1;
  }
  // all waves are past their LDS reads here: smem is reusable.

  if (mode == EP_KV && n0 >= 1024) {
    // ---- V half: LDS-transposed coalesced epilogue ----
    #pragma unroll
    for (int mi = 0; mi < 4; ++mi) {
      #pragma unroll
      for (int reg = 0; reg < 4; ++reg) {
        const int rowl = wm + mi * 16 + quad * 4 + reg;
        const int bbl  = rowl & 7;
        const int tl   = rowl >> 3;
        #pragma unroll
        for (int ni = 0; ni < 4; ++ni) {
          const int coll = wn + ni * 16 + l15;          // 0..127
          const int hn2  = coll >> 6;
          const int d    = coll & 63;
          const int rowid = (bbl * 2 + hn2) * 64 + d;
          smem[tl * 1024 + (rowid ^ (tl << 1))] =
              (short)bfbits(acc[mi][ni][reg]);
        }
      }
    }
    __syncthreads();
    // read phase: each thread emits 4 vT rows (16 t each) as 2x16B stores
    const int hnb = (n0 >> 6) - 16;        // head base for this block
    const int t0  = m0 >> 3;
    #pragma unroll
    for (int p = 0; p < 4; ++p) {
      const int r   = p * 256 + tid;       // rowid 0..1023
      const int bbl = r >> 7;
      const int hn2 = (r >> 6) & 1;
      const int d   = r & 63;
      unsigned short tmp[16];
      #pragma unroll
      for (int tl = 0; tl < 16; ++tl)
        tmp[tl] = (unsigned short)smem[tl * 1024 + (r ^ (tl << 1))];
      bf16* dst = vto + ((size_t)(bbl * 16 + hnb + hn2) * 64 + d) * 1024 + t0;
      *(frag8*)dst       = *(const frag8*)&tmp[0];
      *(frag8*)(dst + 8) = *(const frag8*)&tmp[8];
    }
    return;
  }

  #pragma unroll
  for (int mi = 0; mi < 4; ++mi) {
    #pragma unroll
    for (int reg = 0; reg < 4; ++reg) {
      const int rowl = wm + mi * 16 + quad * 4 + reg;
      const int row  = m0 + rowl;
      if (mode == EP_PLAIN) {
        bf16* orow = out + (size_t)row * N;
        const TRES* rrow = res ? res + (size_t)row * N : nullptr;
        #pragma unroll
        for (int ni = 0; ni < 4; ++ni) {
          const int col = n0 + wn + ni * 16 + l15;
          float v = acc[mi][ni][reg];
          if (bias) v += bias[col];
          if (relu) v = fmaxf(v, 0.f);
          if (rrow) v += tof(rrow[col]);
          orow[col] = f2bf(v);
        }
      } else if (mode == EP_KV) {
        // K half (n0 < 1024): direct stores, 32B/quad chunks
        const int t = row >> 3, bb = row & 7;
        #pragma unroll
        for (int ni = 0; ni < 4; ++ni) {
          const int col = n0 + wn + ni * 16 + l15;
          const int hn = col >> 6, d = col & 63;
          kbo[((size_t)(bb * 16 + hn) * 1024 + t) * 64 + d] =
              f2bf(acc[mi][ni][reg]);
        }
      } else if (mode == EP_Q) {
        // rows are cat rows 4096.. -> t = 512 + row>>3, tq = row>>3
        const int tq = row >> 3, bb = row & 7;
        #pragma unroll
        for (int ni = 0; ni < 4; ++ni) {
          const int col = n0 + wn + ni * 16 + l15;  // 0..1023
          const int hn = col >> 6, d = col & 63;
          const float v = acc[mi][ni][reg];
          const size_t idx = ((size_t)(bb * 16 + hn) * 512 + tq) * 64 + d;
          qwb[idx] = f2bf(v + rwbias[col]);
          qrb[idx] = f2bf(v + rrbias[col]);
        }
      } else { // EP_RK
        #pragma unroll
        for (int ni = 0; ni < 4; ++ni) {
          const int col = n0 + wn + ni * 16 + l15;
          const int hn = col >> 6, d = col & 63;
          qwb[((size_t)hn * 1024 + row) * 64 + d] = f2bf(acc[mi][ni][reg]);
        }
      }
    }
  }
}

// Fused MFMA attention v7: KVBLK 128 -> 64, p_lds XOR-compacted.
// R5 counters: fattn latency-bound at Occupancy 25% -- LDS 49KB allowed only
// 3 blocks/CU while the grid assigns 4 (makespan x4/3 + too few waves/SIMD
// to hide staging/L2 latency). v7: sK 8KB + sV 8KB + p_lds 8KB (pad removed
// via 16B-granular XOR on BOTH write and read sides, rule #21) = 24KB ->
// all 4 assigned blocks/CU co-resident (VGPR-capped 4 waves/SIMD), per-tile
// staging drain halves. Tile count doubles (more reduce/sync work, the
// accepted cost; LDS-pipe load is the fallback suspect if this nulls).
__global__ __launch_bounds__(256, 4)
void fattn(const bf16* __restrict__ qw, const bf16* __restrict__ qr,
           const bf16* __restrict__ kb, const bf16* __restrict__ vT,
           const bf16* __restrict__ rk, bf16* __restrict__ avec)
{
  __shared__ __align__(16) short sK[4096];   // 64 j x 64 d bf16, swizzled (8 KB)
  __shared__ __align__(16) short sV[4096];   // 64 d x 64 j bf16, swizzled (8 KB)
  __shared__ __align__(16) unsigned short p_lds[4][16][64]; // 8 KB, XOR layout
  const int tid  = threadIdx.x;
  const int wave = tid >> 6, lane = tid & 63;
  const int quad = lane >> 4, l15 = lane & 15;
  // XCD-locality decode: bid = r + 8*(phi + 16*it), pair = r + 8*phi
  const int bid = blockIdx.x;
  const int r_  = bid & 7;
  const int s_  = bid >> 3;
  const int phi = s_ & 15;
  const int it  = s_ >> 4;            // i-tile 0..7
  const int pr  = r_ + 8 * phi;       // (h,b) pair 0..127
  const int h   = pr & 15;
  const int b   = pr >> 4;
  const int i0  = it * 64;
  const int iw  = i0 + wave * 16;
  const size_t bh = (size_t)b * 16 + h;
  const bf16* kp = kb + bh * 1024 * 64;
  const bf16* vp = vT + bh * 64 * 1024;
  const bf16* rp = rk + (size_t)h * 1024 * 64;

  frag8 aqw[2], aqr[2];
  {
    const bf16* r0 = qw + (bh * 512 + iw + l15) * 64 + quad * 8;
    aqw[0] = *(const frag8*)r0;
    aqw[1] = *(const frag8*)(r0 + 32);
    const bf16* r1 = qr + (bh * 512 + iw + l15) * 64 + quad * 8;
    aqr[0] = *(const frag8*)r1;
    aqr[1] = *(const frag8*)(r1 + 32);
  }

  f32x4 accO[4] = {};
  float m_run[4], l_run[4];
  #pragma unroll
  for (int rg = 0; rg < 4; ++rg) { m_run[rg] = -INFINITY; l_run[rg] = 0.f; }

  // block-uniform step count (i_last = i0+63); low waves' extra tiles are
  // fully masked (s=-inf -> pv=0 -> no contribution)
  const int nsteps = ((i0 + 63 + 512) >> 6) + 1;
  const int offb   = 15 + l15 - quad * 4;

  // stage j-tile [j0s, j0s+64) of K and V into sK/sV (8 KB each).
  // Linear LDS write (gload_lds, 2 chunks of 4 KB), inverse-swizzled source:
  //   content(byte Lb) = src[Lb ^ ((row&7)<<4)], row = Lb>>7 (128 B rows)
  auto stage = [&](int j0s) {
    #pragma unroll
    for (int c = 0; c < 2; ++c) {
      const int Lb = c * 4096 + tid * 16;
      const int r  = Lb >> 7;            // j-row (K) / d-row (V), 0..63
      const int xb = (Lb & 127) ^ ((r & 7) << 4);
      short* dK = (short*)((char*)sK + (c * 4096 + wave * 1024));
      short* dV = (short*)((char*)sV + (c * 4096 + wave * 1024));
      gload_lds16((const bf16*)((const char*)kp + ((size_t)j0s + r) * 128 + xb), dK);
      gload_lds16((const bf16*)((const char*)vp + (size_t)r * 2048 + (size_t)j0s * 2 + xb), dV);
    }
  };
  stage(0);

  for (int jt = 0; jt < nsteps; ++jt) {
    const int j0 = jt << 6;
    // ---- BD first: global rk loads (L2-resident) overlap K/V staging ----
    const int pbase = 496 + j0 - iw;
    f32x4 bsub[5];
    #pragma unroll
    for (int ns = 0; ns < 5; ++ns) {
      const int prow = min(pbase + ns * 16 + l15, 1023);
      const bf16* rrow = rp + (size_t)prow * 64 + quad * 8;
      frag8 br0 = *(const frag8*)rrow;
      frag8 br1 = *(const frag8*)(rrow + 32);
      f32x4 z = {};
      z = __builtin_amdgcn_mfma_f32_16x16x32_bf16(aqr[0], br0, z, 0,0,0);
      bsub[ns] = __builtin_amdgcn_mfma_f32_16x16x32_bf16(aqr[1], br1, z, 0,0,0);
    }
    __syncthreads();   // sK/sV for this tile are resident
    // ---- AC scores from sK (swizzled ds_read_b128) ----
    f32x4 accS[4] = {};
    #pragma unroll
    for (int ns = 0; ns < 4; ++ns) {
      const int row = ns * 16 + l15;
      const int sw  = (row & 7) << 4;
      frag8 bk0 = *(const frag8*)((const char*)sK + ((row * 128 + quad * 16) ^ sw));
      frag8 bk1 = *(const frag8*)((const char*)sK + ((row * 128 + 64 + quad * 16) ^ sw));
      accS[ns] = __builtin_amdgcn_mfma_f32_16x16x32_bf16(aqw[0], bk0, accS[ns], 0,0,0);
      accS[ns] = __builtin_amdgcn_mfma_f32_16x16x32_bf16(aqw[1], bk1, accS[ns], 0,0,0);
    }
    // ---- in-register shift + combine + mask + tile max ----
    float tmax[4] = {-INFINITY, -INFINITY, -INFINITY, -INFINITY};
    #pragma unroll
    for (int ns = 0; ns < 4; ++ns) {
      #pragma unroll
      for (int rg = 0; rg < 4; ++rg) {
        const int o    = offb - rg;                 // [0,30]
        const int srcl = (quad << 4) | (o & 15);
        const float lo = __shfl(bsub[ns][rg],     srcl, 64);
        const float hi = __shfl(bsub[ns + 1][rg], srcl, 64);
        const float bd = (o & 16) ? hi : lo;
        float s = (accS[ns][rg] + bd) * 0.125f;
        const int j = j0 + ns * 16 + l15;
        s = (j > iw + quad * 4 + rg + 512) ? -INFINITY : s;
        accS[ns][rg] = s;
        tmax[rg] = fmaxf(tmax[rg], s);
      }
    }
    #pragma unroll
    for (int off = 1; off < 16; off <<= 1)
      #pragma unroll
      for (int rg = 0; rg < 4; ++rg)
        tmax[rg] = fmaxf(tmax[rg], __shfl_xor(tmax[rg], off, 64));
    // ---- online softmax update ----
    float alpha[4], tsum[4] = {0.f, 0.f, 0.f, 0.f};
    #pragma unroll
    for (int rg = 0; rg < 4; ++rg) {
      const float nm = fmaxf(m_run[rg], tmax[rg]);
      alpha[rg] = __expf(m_run[rg] - nm);
      m_run[rg] = nm;
    }
    #pragma unroll
    for (int ns = 0; ns < 4; ++ns)
      #pragma unroll
      for (int rg = 0; rg < 4; ++rg) {
        const int rl = quad * 4 + rg;
        const float pv = __expf(accS[ns][rg] - m_run[rg]);
        tsum[rg] += pv;
        // XOR-compacted p_lds write (16B-granular, matches frag8 read)
        *(unsigned short*)((char*)&p_lds[wave][rl][0] +
            (((ns * 16 + l15) * 2) ^ ((rl & 7) << 4))) = bfbits(pv);
      }
    #pragma unroll
    for (int off = 1; off < 16; off <<= 1)
      #pragma unroll
      for (int rg = 0; rg < 4; ++rg)
        tsum[rg] += __shfl_xor(tsum[rg], off, 64);
    #pragma unroll
    for (int rg = 0; rg < 4; ++rg)
      l_run[rg] = l_run[rg] * alpha[rg] + tsum[rg];
    #pragma unroll
    for (int nd = 0; nd < 4; ++nd)
      #pragma unroll
      for (int rg = 0; rg < 4; ++rg)
        accO[nd][rg] *= alpha[rg];
    __builtin_amdgcn_wave_barrier();
    // ---- PV from sV (swizzled ds_read_b128) ----
    #pragma unroll
    for (int ks = 0; ks < 2; ++ks) {
      frag8 ap = *(const frag8*)((const char*)&p_lds[wave][l15][0] +
                  ((ks * 64 + quad * 16) ^ ((l15 & 7) << 4)));
      #pragma unroll
      for (int nd = 0; nd < 4; ++nd) {
        const int d = nd * 16 + l15;
        frag8 bv = *(const frag8*)((const char*)sV +
                    ((d * 128 + ks * 64 + quad * 16) ^ ((d & 7) << 4)));
        accO[nd] = __builtin_amdgcn_mfma_f32_16x16x32_bf16(ap, bv, accO[nd], 0,0,0);
      }
    }
    __builtin_amdgcn_wave_barrier();
    __syncthreads();   // all waves done reading sK/sV
    if (jt + 1 < nsteps) stage((jt + 1) << 6);
  }

  #pragma unroll
  for (int rg = 0; rg < 4; ++rg) {
    const int i = iw + quad * 4 + rg;
    const float inv = 1.f / l_run[rg];
    #pragma unroll
    for (int nd = 0; nd < 4; ++nd) {
      const int d = nd * 16 + l15;
      avec[((size_t)i * 8 + b) * 1024 + h * 64 + d] = f2bf(accO[nd][rg] * inv);
    }
  }
}

// row LayerNorm over 1024 cols; one block per row.
template<typename TOUT>
__global__ __launch_bounds__(256)
void ln_kernel(const bf16* __restrict__ x, const float* __restrict__ g,
               const float* __restrict__ be, TOUT* __restrict__ out)
{
  __shared__ float red0[4];
  __shared__ float red1[4];
  const int row = blockIdx.x;
  const int tid = threadIdx.x;
  const bf16* xr = x + (size_t)row * 1024;
  ushort4 u = *(const ushort4*)(xr + (tid << 2));
  const float v0 = u16f(u.x), v1 = u16f(u.y), v2 = u16f(u.z), v3 = u16f(u.w);
  float sum = v0 + v1 + v2 + v3;
  #pragma unroll
  for (int off = 1; off < 64; off <<= 1) sum += __shfl_xor(sum, off, 64);
  if ((tid & 63) == 0) red0[tid >> 6] = sum;
  __syncthreads();
  const float mu = (red0[0] + red0[1] + red0[2] + red0[3]) * (1.f / 1024.f);
  const float d0 = v0 - mu, d1 = v1 - mu, d2 = v2 - mu, d3 = v3 - mu;
  float sq = d0*d0 + d1*d1 + d2*d2 + d3*d3;
  #pragma unroll
  for (int off = 1; off < 64; off <<= 1) sq += __shfl_xor(sq, off, 64);
  if ((tid & 63) == 0) red1[tid >> 6] = sq;
  __syncthreads();
  const float var = (red1[0] + red1[1] + red1[2] + red1[3]) * (1.f / 1024.f);
  const float inv = 1.f / sqrtf(var + 1e-5f);
  const int c = tid << 2;
  float4 ug = *(const float4*)(g + c);
  float4 ub = *(const float4*)(be + c);
  TOUT* orow = out + (size_t)row * 1024;
  orow[c+0] = (TOUT)(d0 * inv * ug.x + ub.x);
  orow[c+1] = (TOUT)(d1 * inv * ug.y + ub.y);
  orow[c+2] = (TOUT)(d2 * inv * ug.z + ub.z);
  orow[c+3] = (TOUT)(d3 * inv * ug.w + ub.w);
}

extern "C" void kernel_launch(void* const* d_in, const int* in_sizes, int n_in,
                              void* d_out, int out_size, void* d_ws, size_t ws_size,
                              hipStream_t stream)
{
  const float* w    = (const float*)d_in[0];
  const float* r    = (const float*)d_in[1];
  const float* rwb  = (const float*)d_in[2];
  const float* rrb  = (const float*)d_in[3];
  const float* mems = (const float*)d_in[4];
  // d_in[5] = attn_mask: deterministic (j > i + 512), computed in-kernel
  const float* Wqkv = (const float*)d_in[6];
  const float* Wr   = (const float*)d_in[7];
  const float* Wo   = (const float*)d_in[8];
  const float* ln1g = (const float*)d_in[9];
  const float* ln1b = (const float*)d_in[10];
  const float* W1   = (const float*)d_in[11];
  const float* b1   = (const float*)d_in[12];
  const float* W2   = (const float*)d_in[13];
  const float* b2   = (const float*)d_in[14];
  const float* ln2g = (const float*)d_in[15];
  const float* ln2b = (const float*)d_in[16];

  // Workspace (bf16), liveness-aliased, peak 94 MiB (layout unchanged from R5)
  const size_t MB = 1u << 20;
  char* p = (char*)d_ws;
  bf16* catb  = (bf16*)(p +  0 * MB);
  bf16* wqkvb = (bf16*)(p + 16 * MB);
  bf16* wrb   = (bf16*)(p + 22 * MB);
  bf16* wob   = (bf16*)(p + 24 * MB);
  bf16* w1b   = (bf16*)(p + 26 * MB);
  bf16* w2b   = (bf16*)(p + 34 * MB);
  bf16* qwbuf = (bf16*)(p + 42 * MB);
  bf16* qrbuf = (bf16*)(p + 50 * MB);
  bf16* kbuf  = (bf16*)(p + 58 * MB);
  bf16* vTbuf = (bf16*)(p + 74 * MB);
  bf16* rkbuf = (bf16*)(p + 90 * MB);
  bf16* rb    = (bf16*)(p + 92 * MB);
  bf16* avec  = (bf16*)(p +  0 * MB);
  bf16* x1    = (bf16*)(p +  8 * MB);
  bf16* o1    = (bf16*)(p + 42 * MB);
  bf16* x2    = (bf16*)(p + 50 * MB);
  bf16* h     = (bf16*)(p + 58 * MB);

  dim3 blk(256);
  // 0. fp32 -> bf16 converts (one batched launch)
  {
    CvtArgs a;
    const int n4w = (4096 * 1024) / 4, n4r = (1024 * 1024) / 4,
              n4qkv = (3072 * 1024) / 4;
    a.src[0] = mems; a.dst[0] = catb;                        int n0_ = n4w;
    a.src[1] = w;    a.dst[1] = catb + (size_t)4096 * 1024;  int n1_ = n4w;
    a.src[2] = r;    a.dst[2] = rb;                          int n2_ = n4r;
    a.src[3] = Wqkv; a.dst[3] = wqkvb;                       int n3_ = n4qkv;
    a.src[4] = Wr;   a.dst[4] = wrb;                         int n4_ = n4r;
    a.src[5] = Wo;   a.dst[5] = wob;                         int n5_ = n4r;
    a.src[6] = W1;   a.dst[6] = w1b;                         int n6_ = n4w;
    a.src[7] = W2;   a.dst[7] = w2b;                         int n7_ = n4w;
    const int ns_[8] = {n0_, n1_, n2_, n3_, n4_, n5_, n6_, n7_};
    a.cum[0] = 0;
    for (int s2 = 0; s2 < 8; ++s2) a.cum[s2 + 1] = a.cum[s2] + ns_[s2];
    cvt8<<<dim3((a.cum[8] + 255) / 256), blk, 0, stream>>>(a);
  }

  // 1a. K/V projection: cat @ Wqkv[1024:3072]^T -> kb (direct) + vT (LDS-coalesced)
  mgemm<float><<<dim3(16, 64), blk, 0, stream>>>(catb, wqkvb + (size_t)1024 * 1024,
        nullptr, (const float*)nullptr, nullptr, nullptr, nullptr, kbuf, vTbuf,
        nullptr, nullptr, 8192, 2048, 1024, EP_KV, 0);
  // 1b. Q projection: only rows t>=512 (cat rows 4096..8191), biases fused
  mgemm<float><<<dim3(8, 32), blk, 0, stream>>>(catb + (size_t)4096 * 1024, wqkvb,
        nullptr, (const float*)nullptr, nullptr, qwbuf, qrbuf, nullptr, nullptr,
        rwb, rrb, 4096, 1024, 1024, EP_Q, 0);
  // 2. rk = r @ Wr^T -> (h,p,d)
  mgemm<float><<<dim3(8, 8), blk, 0, stream>>>(rb, wrb, nullptr, (const float*)nullptr,
        nullptr, rkbuf, nullptr, nullptr, nullptr, nullptr, nullptr,
        1024, 1024, 1024, EP_RK, 0);
  // 3. fused MFMA attention -> avec (1024 blocks, XCD-swizzled, K/V LDS-staged)
  fattn<<<dim3(1024), blk, 0, stream>>>(qwbuf, qrbuf, kbuf, vTbuf, rkbuf, avec);
  // 4. x1 = w + avec @ Wo^T
  mgemm<float><<<dim3(8, 32), blk, 0, stream>>>(avec, wob, nullptr, w,
        x1, nullptr, nullptr, nullptr, nullptr, nullptr, nullptr,
        4096, 1024, 1024, EP_PLAIN, 0);
  // 5. out1 = LN(x1)
  ln_kernel<bf16><<<dim3(4096), blk, 0, stream>>>(x1, ln1g, ln1b, o1);
  // 6. h = relu(out1 @ W1^T + b1)
  mgemm<float><<<dim3(32, 32), blk, 0, stream>>>(o1, w1b, b1, (const float*)nullptr,
        h, nullptr, nullptr, nullptr, nullptr, nullptr, nullptr,
        4096, 4096, 1024, EP_PLAIN, 1);
  // 7. x2 = out1 + h @ W2^T + b2
  mgemm<bf16><<<dim3(8, 32), blk, 0, stream>>>(h, w2b, b2, o1,
        x2, nullptr, nullptr, nullptr, nullptr, nullptr, nullptr,
        4096, 1024, 4096, EP_PLAIN, 0);
  // 8. out = LN(x2) -> fp32
  ln_kernel<float><<<dim3(4096), blk, 0, stream>>>(x2, ln2g, ln2b, (float*)d_out);
}